// Round 11
// baseline (518.419 us; speedup 1.0000x reference)
//
#include <hip/hip_runtime.h>
#include <cmath>

// DHGLayer on MI355X. N=10000, D=128.
// kpre (normalize + split-bf16 feats/W tables, fused) -> ksim (bf16 MFMA sim +
// wave-local top-16; key buffer ALIASED into B-staging LDS -> 32KB, 5 blk/CU)
// -> kmerge -> krerank (f64 exact top-16) -> kvcall (fused vertex conv, all 5
// branches via blockIdx.y; split-bf16 MFMA + bKK + in-register softmax) ->
// kfinal (float4 LDS).
// R10 lesson: ksim pinned at ~110us across 3 variants with Occupancy 26%
// (49.5KB LDS -> 2 blk/CU); scan stall-bound. Keys and B-staging have disjoint
// lifetimes per tile -> alias into one 32KB region (+1 barrier/tile) -> 5 blk/CU.
// kfinal inner loops were scalar ds_read_b32-heavy -> float4. 8 -> 6 dispatches.

#define N_NODES 10000
#define D 128
#define DQ 32
#define NCB 3
#define T_HE 5
#define HID_SZ 32
#define NCH 16
#define CHUNK 625      // 16 * 625 = 10000
#define TOPK 16
#define TOPM 32

typedef __attribute__((ext_vector_type(8))) short short8;
typedef __attribute__((ext_vector_type(4))) float f32x4;
typedef __attribute__((ext_vector_type(16))) float f32x16;

// ---------------- helpers ----------------
__device__ __forceinline__ unsigned bf16rne(float f) {
  unsigned u = __float_as_uint(f);
  return (u + 0x7FFFu + ((u >> 16) & 1u)) >> 16;
}
__device__ __forceinline__ float2 bfpair(unsigned u) {
  float2 r;
  r.x = __uint_as_float(u << 16);
  r.y = __uint_as_float(u & 0xFFFF0000u);
  return r;
}

// ---------------- fused prep: normalize + split-bf16 feats + split-bf16 W ----------------
// grid 2884: bx<2500 -> 4 feature rows (64 threads each); else -> W pair chunks.
__global__ __launch_bounds__(256) void kpre(const float* __restrict__ feats,
                                            const float* __restrict__ wc,
                                            const float* __restrict__ wn,
                                            const float* __restrict__ wstr,
                                            unsigned short* __restrict__ xnh,
                                            unsigned short* __restrict__ fHi,
                                            unsigned short* __restrict__ fLo,
                                            double* __restrict__ normD,
                                            unsigned short* __restrict__ wHi,
                                            unsigned short* __restrict__ wLo) {
  int bx = blockIdx.x;
  int tid = threadIdx.x;
  if (bx < 2500) {
    int n = bx * 4 + (tid >> 6);
    int lane = tid & 63;
    float2 v = ((const float2*)(feats + (size_t)n * D))[lane];
    unsigned hxu = bf16rne(v.x), hyu = bf16rne(v.y);
    float hxf = __uint_as_float(hxu << 16), hyf = __uint_as_float(hyu << 16);
    unsigned lxu = bf16rne(v.x - hxf), lyu = bf16rne(v.y - hyf);
    ((unsigned*)(fHi + (size_t)n * D))[lane] = hxu | (hyu << 16);
    ((unsigned*)(fLo + (size_t)n * D))[lane] = lxu | (lyu << 16);
    double ss = (double)v.x * (double)v.x + (double)v.y * (double)v.y;
#pragma unroll
    for (int o = 32; o > 0; o >>= 1) ss += __shfl_xor(ss, o);
    double nd = fmax(sqrt(ss), 1e-12);
    if (lane == 0) normD[n] = nd;
    float inv = (float)(1.0 / nd);
    ((unsigned*)(xnh + (size_t)n * D))[lane] = bf16rne(v.x * inv) | (bf16rne(v.y * inv) << 16);
  } else {
    int p = (bx - 2500) * 256 + tid;
    if (p >= 98304) return;
    int e = p * 2;
    float2 v;
    if (e < 32768) v = *(const float2*)(wc + e);
    else if (e < 65536) v = *(const float2*)(wn + (e - 32768));
    else v = *(const float2*)(wstr + (e - 65536));
    unsigned hxu = bf16rne(v.x), hyu = bf16rne(v.y);
    float hxf = __uint_as_float(hxu << 16), hyf = __uint_as_float(hyu << 16);
    unsigned lxu = bf16rne(v.x - hxf), lyu = bf16rne(v.y - hyf);
    ((unsigned*)wHi)[p] = hxu | (hyu << 16);
    ((unsigned*)wLo)[p] = lxu | (lyu << 16);
  }
}

// ---------------- sorting-network helpers ----------------
__device__ __forceinline__ void ceu(unsigned& a, unsigned& b) {
  unsigned lo = min(a, b), hi = max(a, b);
  a = lo; b = hi;
}
__device__ __forceinline__ void ceu64(unsigned long long& a, unsigned long long& b) {
  unsigned long long lo = min(a, b), hi = max(a, b);
  a = lo; b = hi;
}
__device__ __forceinline__ void sort16_asc(unsigned (&v)[16]) {
#pragma unroll
  for (int k = 2; k <= 16; k <<= 1) {
#pragma unroll
    for (int j = k >> 1; j > 0; j >>= 1) {
#pragma unroll
      for (int i = 0; i < 16; i++) {
        int x = i ^ j;
        if (x > i) {
          if ((i & k) == 0) ceu(v[i], v[x]);
          else ceu(v[x], v[i]);
        }
      }
    }
  }
}
__device__ __forceinline__ void merge16_asc(unsigned (&run)[16], const unsigned (&b)[16]) {
  unsigned m[16];
#pragma unroll
  for (int i = 0; i < 16; i++) m[i] = max(run[i], b[15 - i]);
#pragma unroll
  for (int j = 8; j > 0; j >>= 1) {
#pragma unroll
    for (int i = 0; i < 16; i++) {
      if ((i & j) == 0) ceu(m[i], m[i + j]);
    }
  }
#pragma unroll
  for (int i = 0; i < 16; i++) run[i] = m[i];
}

// ---------------- bf16 MFMA sim + per-chunk top-16 ----------------
// grid (79 row-blocks of 128, 16 chunks of 625). 4 waves; wave w owns rows
// w*32..+31 x all 128 cols. Keys ALIAS the 32KB B-staging buffer (disjoint
// lifetimes within a tile; extra barrier after MFMA reads drain before key
// writes clobber B). LDS 32KB -> 5 blocks/CU (vs 49.5KB/2 -> Occupancy 26%,
// VALUBusy 50% at 110us in R10).
__global__ __launch_bounds__(256, 5) void ksim(const unsigned short* __restrict__ xnh,
                                               unsigned* __restrict__ cand) {
  __shared__ unsigned char smem[32768];
  short* Bb = (short*)smem;
  int tid = threadIdx.x;
  int w = tid >> 6, lane = tid & 63, l31 = lane & 31, lh = lane >> 5;
  unsigned* kbw = (unsigned*)smem + w * (32 * 35);   // per-wave 4.48KB, aliases Bb
  int row0 = blockIdx.x * 128 + w * 32;
  int chunk = blockIdx.y;
  int cbase = chunk * CHUNK;

  short8 afr[8];
  {
    int ar = min(row0 + l31, N_NODES - 1);
    const short8* ap = (const short8*)(xnh + (size_t)ar * D);
#pragma unroll
    for (int ks = 0; ks < 8; ks++) afr[ks] = ap[ks * 2 + lh];
  }

  unsigned run[16];
#pragma unroll
  for (int s = 0; s < 16; s++) run[s] = 0u;
  int srow = lane >> 1, soff = (lane & 1) * 16;

  for (int ti = 0; ti < 5; ti++) {
    int tb = cbase + ti * 128;
    __syncthreads();   // prev tile's key-scan reads done
    {  // stage B (cols tb..tb+127) k-major; fully coalesced
      int ci = tid >> 1, h = tid & 1;
      int gcol = min(tb + ci, N_NODES - 1);
      const short8* gp = (const short8*)(xnh + (size_t)gcol * D);
      short8* bp = (short8*)Bb;
#pragma unroll
      for (int i = 0; i < 8; i++) bp[(h * 8 + i) * 128 + ci] = gp[h * 8 + i];
    }
    __syncthreads();

    f32x16 acc[4];
#pragma unroll
    for (int ni = 0; ni < 4; ni++)
#pragma unroll
      for (int r = 0; r < 16; r++) acc[ni][r] = 0.f;
    const short8* bv = (const short8*)Bb;
#pragma unroll
    for (int ks = 0; ks < 8; ks++) {
      int kp = ks * 2 + lh;
#pragma unroll
      for (int ni = 0; ni < 4; ni++) {
        short8 bf = bv[kp * 128 + ni * 32 + l31];
        acc[ni] = __builtin_amdgcn_mfma_f32_32x32x16_bf16(afr[ks], bf, acc[ni], 0, 0, 0);
      }
    }
    __syncthreads();   // all waves' B reads drained; safe to clobber with keys

#pragma unroll
    for (int ni = 0; ni < 4; ni++) {
      int cb2 = ti * 128 + ni * 32;
#pragma unroll
      for (int reg = 0; reg < 16; reg++) {
        int r = (reg & 3) + 8 * (reg >> 2) + 4 * lh;
        int cic = cb2 + l31;
        unsigned bb = __float_as_uint(acc[ni][reg]);
        unsigned mu = (bb & 0x80000000u) ? ~bb : (bb | 0x80000000u);
        unsigned key = (cic < CHUNK) ? ((mu & 0xFFFFFC00u) | (unsigned)(1023 - cic)) : 0u;
        kbw[r * 35 + l31] = key;
      }
      unsigned bt[16];
      const unsigned* rp = &kbw[srow * 35 + soff];
#pragma unroll
      for (int q = 0; q < 4; q++) {
        uint4 t4 = *(const uint4*)(rp + q * 4);
        bt[q * 4 + 0] = t4.x; bt[q * 4 + 1] = t4.y;
        bt[q * 4 + 2] = t4.z; bt[q * 4 + 3] = t4.w;
      }
      sort16_asc(bt);
      merge16_asc(run, bt);
    }
  }
  {
    unsigned other[16];
#pragma unroll
    for (int s = 0; s < 16; s++) other[s] = (unsigned)__shfl_xor((int)run[s], 1);
    merge16_asc(run, other);
  }
  int grow = row0 + srow;
  if ((lane & 1) == 0 && grow < N_NODES) {
    unsigned* o = cand + ((size_t)grow * NCH + chunk) * 16;
#pragma unroll
    for (int i = 0; i < 16; i += 4)
      *(uint4*)(o + i) = make_uint4(run[i], run[i + 1], run[i + 2], run[i + 3]);
  }
}

// ---------------- merge chunk keys -> top-32 candidate cols ----------------
__global__ __launch_bounds__(64) void kmerge(const unsigned* __restrict__ cand,
                                             int* __restrict__ candIdx) {
  int row = blockIdx.x * 64 + threadIdx.x;
  if (row >= N_NODES) return;
  unsigned long long run[TOPM];
#pragma unroll
  for (int s = 0; s < TOPM; s++) run[s] = 0ull;
  const uint4* c4 = (const uint4*)(cand + (size_t)row * (NCH * 16));
  for (int ch = 0; ch < NCH; ch++) {
    unsigned b[16];
#pragma unroll
    for (int q = 0; q < 4; q++) {
      uint4 t = c4[ch * 4 + q];
      b[q * 4 + 0] = t.x; b[q * 4 + 1] = t.y;
      b[q * 4 + 2] = t.z; b[q * 4 + 3] = t.w;
    }
    unsigned base = (unsigned)(ch * CHUNK);
    unsigned long long b64[16];
#pragma unroll
    for (int s = 0; s < 16; s++) {
      unsigned k = b[s];
      unsigned gcol = base + (1023u - (k & 1023u));
      b64[s] = ((unsigned long long)(k >> 10) << 32) | (unsigned long long)(~gcol);
    }
#pragma unroll
    for (int i = 0; i < 16; i++) run[i] = max(run[i], b64[15 - i]);
#pragma unroll
    for (int j = 16; j > 0; j >>= 1)
#pragma unroll
      for (int i = 0; i < TOPM; i++)
        if ((i & j) == 0) ceu64(run[i], run[i + j]);
  }
  int4* o4 = (int4*)(candIdx + (size_t)row * TOPM);
#pragma unroll
  for (int s = 0; s < TOPM; s += 4) {
    int4 o;
    o.x = (int)(~(unsigned)(run[s + 0] & 0xFFFFFFFFull));
    o.y = (int)(~(unsigned)(run[s + 1] & 0xFFFFFFFFull));
    o.z = (int)(~(unsigned)(run[s + 2] & 0xFFFFFFFFull));
    o.w = (int)(~(unsigned)(run[s + 3] & 0xFFFFFFFFull));
    o4[s >> 2] = o;
  }
}

// ---------------- f64 exact re-rank of 32 candidates -> knn top-16 ----------------
__global__ __launch_bounds__(256) void krerank(const float* __restrict__ feats,
                                               const double* __restrict__ normD,
                                               const int* __restrict__ candIdx,
                                               int* __restrict__ knn) {
  __shared__ float rowF[D];
  __shared__ double simL[TOPM];
  __shared__ int idxL[TOPM];
  int row = blockIdx.x;
  int tid = threadIdx.x;
  if (tid < DQ)
    ((float4*)rowF)[tid] = ((const float4*)(feats + (size_t)row * D))[tid];
  int c = tid >> 3, part = tid & 7;
  int cnd = candIdx[(size_t)row * TOPM + c];
  __syncthreads();
  const float4* f4 = (const float4*)(feats + (size_t)cnd * D);
  double acc = 0.0;
#pragma unroll
  for (int g = 0; g < 4; g++) {
    float4 v = f4[part * 4 + g];
    const float* rf = &rowF[(part * 4 + g) * 4];
    acc = fma((double)v.x, (double)rf[0], acc);
    acc = fma((double)v.y, (double)rf[1], acc);
    acc = fma((double)v.z, (double)rf[2], acc);
    acc = fma((double)v.w, (double)rf[3], acc);
  }
  acc += __shfl_down(acc, 4);
  acc += __shfl_down(acc, 2);
  acc += __shfl_down(acc, 1);
  if (part == 0) {
    simL[c] = acc / (normD[row] * normD[cnd]);
    idxL[c] = cnd;
  }
  __syncthreads();
  if (tid < TOPM) {
    double s = simL[tid];
    int idx = idxL[tid];
    int rank = 0;
#pragma unroll
    for (int o = 0; o < TOPM; o++) {
      double so = simL[o];
      int io = idxL[o];
      rank += (so > s || (so == s && io < idx)) ? 1 : 0;
    }
    if (rank < TOPK) knn[(size_t)row * TOPK + rank] = idx;
  }
}

// ---------------- FUSED vertex conv, all 5 branches (z = 0..2 cluster, 3 knn, 4 struct) ----------------
// grid (625, 5), 256 thr = 4 waves, 16 nodes/block. Waves split the i-loop.
// Split-bf16 MFMA mult + bKK + shfl softmax; partial coef -> LDS -> reduce ->
// combine from x = hi+lo.
__global__ __launch_bounds__(256) void kvcall(
    const unsigned short* __restrict__ fHi, const unsigned short* __restrict__ fLo,
    const int* __restrict__ cluster_idx, const int* __restrict__ knn,
    const int* __restrict__ struct_idx,
    const unsigned short* __restrict__ wHi, const unsigned short* __restrict__ wLo,
    const float* __restrict__ bKK_c, const float* __restrict__ bKK_n,
    const float* __restrict__ bKK_s,
    const float* __restrict__ wK1_c, const float* __restrict__ bK1_c,
    const float* __restrict__ wK1_n, const float* __restrict__ bK1_n,
    const float* __restrict__ wK1_s, const float* __restrict__ bK1_s,
    float* __restrict__ hx) {
  __shared__ int idxL[16][33];
  __shared__ float coefP[4][16][33];
  __shared__ float coefS[16][33];
  int tid = threadIdx.x;
  int z = blockIdx.y;
  int n0 = blockIdx.x * 16;             // 625*16 = 10000 exactly
  int w = tid >> 6, lane = tid & 63, l15 = lane & 15, quad = lane >> 4;
  const short8* fHh = (const short8*)fHi;
  const short8* fHl = (const short8*)fLo;

  if (z < 4) {
    // ---------------- K = 16 ----------------
    const int* idxTab; int istr, ioff, woff;
    const float* bKK; const float* wK1; const float* bK1p;
    if (z < 3) { idxTab = cluster_idx; istr = NCB * 16; ioff = z * 16; woff = 0;     bKK = bKK_c; wK1 = wK1_c; bK1p = bK1_c; }
    else       { idxTab = knn;         istr = 16;       ioff = 0;      woff = 32768; bKK = bKK_n; wK1 = wK1_n; bK1p = bK1_n; }
    {
      int nn = tid >> 4, i = tid & 15;
      idxL[nn][i] = idxTab[(size_t)(n0 + nn) * istr + ioff + i];
    }
    __syncthreads();
    const short8* wHh = (const short8*)(wHi + woff);
    const short8* wHl = (const short8*)(wLo + woff);
    f32x4 coef = {0.f, 0.f, 0.f, 0.f};
#pragma unroll
    for (int ii = 0; ii < 4; ii++) {
      int i = w * 4 + ii;
      int rowi = idxL[l15][i];
      float bkk = bKK[i * 16 + l15];
      f32x4 acc = {0.f, 0.f, 0.f, 0.f};
#pragma unroll
      for (int kc = 0; kc < 4; kc++) {
        short8 ah = fHh[(size_t)rowi * 16 + kc * 4 + quad];
        short8 al = fHl[(size_t)rowi * 16 + kc * 4 + quad];
        short8 bh = wHh[((size_t)i * 16 + l15) * 16 + kc * 4 + quad];
        short8 bl = wHl[((size_t)i * 16 + l15) * 16 + kc * 4 + quad];
        acc = __builtin_amdgcn_mfma_f32_16x16x32_bf16(ah, bh, acc, 0, 0, 0);
        acc = __builtin_amdgcn_mfma_f32_16x16x32_bf16(ah, bl, acc, 0, 0, 0);
        acc = __builtin_amdgcn_mfma_f32_16x16x32_bf16(al, bh, acc, 0, 0, 0);
      }
      float wki = wK1[i];
#pragma unroll
      for (int r = 0; r < 4; r++) {
        float v = acc[r] + bkk;
        float mx = v;
#pragma unroll
        for (int msk = 1; msk < 16; msk <<= 1) mx = fmaxf(mx, __shfl_xor(mx, msk));
        float e = __expf(v - mx);
        float s = e;
#pragma unroll
        for (int msk = 1; msk < 16; msk <<= 1) s += __shfl_xor(s, msk);
        coef[r] += wki * (e / s);
      }
    }
#pragma unroll
    for (int r = 0; r < 4; r++) coefP[w][quad * 4 + r][l15] = coef[r];
    __syncthreads();
    {
      int nn = tid >> 4, j = tid & 15;
      coefS[nn][j] = coefP[0][nn][j] + coefP[1][nn][j] + coefP[2][nn][j] + coefP[3][nn][j];
    }
    __syncthreads();
    {
      int nl = tid >> 4, g = tid & 15;
      float bk1 = bK1p[0];
      float a8[8];
#pragma unroll
      for (int t = 0; t < 8; t++) a8[t] = bk1;
      for (int j = 0; j < 16; j++) {
        float cf = coefS[nl][j];
        int rowj = idxL[nl][j];
        uint4 h4 = *(const uint4*)(fHi + (size_t)rowj * D + g * 8);
        uint4 l4 = *(const uint4*)(fLo + (size_t)rowj * D + g * 8);
        unsigned hv[4] = {h4.x, h4.y, h4.z, h4.w};
        unsigned lv[4] = {l4.x, l4.y, l4.z, l4.w};
#pragma unroll
        for (int q = 0; q < 4; q++) {
          float2 hp = bfpair(hv[q]), lp = bfpair(lv[q]);
          a8[q * 2 + 0] = fmaf(cf, hp.x + lp.x, a8[q * 2 + 0]);
          a8[q * 2 + 1] = fmaf(cf, hp.y + lp.y, a8[q * 2 + 1]);
        }
      }
      int node = n0 + nl;
      float4* o = (float4*)(hx + ((size_t)node * T_HE + z) * D + g * 8);
      o[0] = make_float4(a8[0], a8[1], a8[2], a8[3]);
      o[1] = make_float4(a8[4], a8[5], a8[6], a8[7]);
    }
  } else {
    // ---------------- K = 32 (struct) ----------------
    for (int e = tid; e < 512; e += 256) {
      int nn = e >> 5, i = e & 31;
      idxL[nn][i] = struct_idx[(size_t)(n0 + nn) * 32 + i];
    }
    __syncthreads();
    const short8* wHh = (const short8*)(wHi + 65536);
    const short8* wHl = (const short8*)(wLo + 65536);
    f32x4 coef0 = {0.f, 0.f, 0.f, 0.f};
    f32x4 coef1 = {0.f, 0.f, 0.f, 0.f};
#pragma unroll
    for (int ii = 0; ii < 8; ii++) {
      int i = w * 8 + ii;
      int rowi = idxL[l15][i];
      float bk0 = bKK_s[i * 32 + l15];
      float bk1v = bKK_s[i * 32 + 16 + l15];
      f32x4 a0 = {0.f, 0.f, 0.f, 0.f};
      f32x4 a1 = {0.f, 0.f, 0.f, 0.f};
#pragma unroll
      for (int kc = 0; kc < 4; kc++) {
        short8 ah = fHh[(size_t)rowi * 16 + kc * 4 + quad];
        short8 al = fHl[(size_t)rowi * 16 + kc * 4 + quad];
        short8 b0h = wHh[((size_t)i * 32 + l15) * 16 + kc * 4 + quad];
        short8 b0l = wHl[((size_t)i * 32 + l15) * 16 + kc * 4 + quad];
        short8 b1h = wHh[((size_t)i * 32 + 16 + l15) * 16 + kc * 4 + quad];
        short8 b1l = wHl[((size_t)i * 32 + 16 + l15) * 16 + kc * 4 + quad];
        a0 = __builtin_amdgcn_mfma_f32_16x16x32_bf16(ah, b0h, a0, 0, 0, 0);
        a0 = __builtin_amdgcn_mfma_f32_16x16x32_bf16(ah, b0l, a0, 0, 0, 0);
        a0 = __builtin_amdgcn_mfma_f32_16x16x32_bf16(al, b0h, a0, 0, 0, 0);
        a1 = __builtin_amdgcn_mfma_f32_16x16x32_bf16(ah, b1h, a1, 0, 0, 0);
        a1 = __builtin_amdgcn_mfma_f32_16x16x32_bf16(ah, b1l, a1, 0, 0, 0);
        a1 = __builtin_amdgcn_mfma_f32_16x16x32_bf16(al, b1h, a1, 0, 0, 0);
      }
      float wki = wK1_s[i];
#pragma unroll
      for (int r = 0; r < 4; r++) {
        float v0 = a0[r] + bk0, v1 = a1[r] + bk1v;
        float mx = fmaxf(v0, v1);
#pragma unroll
        for (int msk = 1; msk < 16; msk <<= 1) mx = fmaxf(mx, __shfl_xor(mx, msk));
        float e0 = __expf(v0 - mx), e1 = __expf(v1 - mx);
        float s = e0 + e1;
#pragma unroll
        for (int msk = 1; msk < 16; msk <<= 1) s += __shfl_xor(s, msk);
        float inv = wki / s;
        coef0[r] += e0 * inv;
        coef1[r] += e1 * inv;
      }
    }
#pragma unroll
    for (int r = 0; r < 4; r++) {
      coefP[w][quad * 4 + r][l15] = coef0[r];
      coefP[w][quad * 4 + r][l15 + 16] = coef1[r];
    }
    __syncthreads();
    for (int e = tid; e < 512; e += 256) {
      int nn = e >> 5, j = e & 31;
      coefS[nn][j] = coefP[0][nn][j] + coefP[1][nn][j] + coefP[2][nn][j] + coefP[3][nn][j];
    }
    __syncthreads();
    {
      int nl = tid >> 4, g = tid & 15;
      float bk1 = bK1_s[0];
      float a8[8];
#pragma unroll
      for (int t = 0; t < 8; t++) a8[t] = bk1;
      for (int j = 0; j < 32; j++) {
        float cf = coefS[nl][j];
        int rowj = idxL[nl][j];
        uint4 h4 = *(const uint4*)(fHi + (size_t)rowj * D + g * 8);
        uint4 l4 = *(const uint4*)(fLo + (size_t)rowj * D + g * 8);
        unsigned hv[4] = {h4.x, h4.y, h4.z, h4.w};
        unsigned lv[4] = {l4.x, l4.y, l4.z, l4.w};
#pragma unroll
        for (int q = 0; q < 4; q++) {
          float2 hp = bfpair(hv[q]), lp = bfpair(lv[q]);
          a8[q * 2 + 0] = fmaf(cf, hp.x + lp.x, a8[q * 2 + 0]);
          a8[q * 2 + 1] = fmaf(cf, hp.y + lp.y, a8[q * 2 + 1]);
        }
      }
      int node = n0 + nl;
      float4* o = (float4*)(hx + ((size_t)node * T_HE + 4) * D + g * 8);
      o[0] = make_float4(a8[0], a8[1], a8[2], a8[3]);
      o[1] = make_float4(a8[4], a8[5], a8[6], a8[7]);
    }
  }
}

// ---------------- edge attention + fc (float4 LDS) ----------------
__global__ __launch_bounds__(256) void kfinal(const float* __restrict__ hx,
    const float* __restrict__ w1, const float* __restrict__ b1,
    const float* __restrict__ w2, const float* __restrict__ b2p,
    const float* __restrict__ fcw, const float* __restrict__ fcb,
    float* __restrict__ out) {
  __shared__ float xL[8][T_HE][D];
  __shared__ float hL[8][T_HE][HID_SZ];
  __shared__ float scL[8][T_HE];
  __shared__ float aggL[8][D];
  int tid = threadIdx.x;
  int n0 = blockIdx.x * 8;
  const float4* hx4 = (const float4*)hx;
  for (int q = tid; q < 8 * T_HE * DQ; q += 256) {
    int nn = q / (T_HE * DQ);
    int rem = q - nn * (T_HE * DQ);
    int t = rem / DQ;
    int dq = rem & 31;
    int node = n0 + nn;
    float4 val = make_float4(0.f, 0.f, 0.f, 0.f);
    if (node < N_NODES) val = hx4[((size_t)node * T_HE + t) * DQ + dq];
    *(float4*)&xL[nn][t][dq << 2] = val;
  }
  __syncthreads();
  for (int q = tid; q < 8 * T_HE * HID_SZ; q += 256) {
    int nn = q / (T_HE * HID_SZ);
    int rem = q - nn * (T_HE * HID_SZ);
    int t = rem / HID_SZ;
    int hh = rem & (HID_SZ - 1);
    float acc = b1[hh];
    const float4* xv4 = (const float4*)xL[nn][t];
    for (int dq = 0; dq < 32; dq++) {
      float4 xv = xv4[dq];
      int db = dq * 4;
      acc = fmaf(xv.x, w1[(db + 0) * HID_SZ + hh], acc);
      acc = fmaf(xv.y, w1[(db + 1) * HID_SZ + hh], acc);
      acc = fmaf(xv.z, w1[(db + 2) * HID_SZ + hh], acc);
      acc = fmaf(xv.w, w1[(db + 3) * HID_SZ + hh], acc);
    }
    hL[nn][t][hh] = fmaxf(acc, 0.f);
  }
  __syncthreads();
  if (tid < 8 * T_HE) {
    int nn = tid / T_HE, t = tid % T_HE;
    float acc = b2p[0];
    for (int hh = 0; hh < HID_SZ; hh++) acc = fmaf(hL[nn][t][hh], w2[hh], acc);
    scL[nn][t] = acc;
  }
  __syncthreads();
  if (tid < 8) {
    float mx = -1e30f;
#pragma unroll
    for (int t = 0; t < T_HE; t++) mx = fmaxf(mx, scL[tid][t]);
    float e[T_HE];
    float s = 0.f;
#pragma unroll
    for (int t = 0; t < T_HE; t++) { e[t] = expf(scL[tid][t] - mx); s += e[t]; }
    float inv = 1.f / s;
#pragma unroll
    for (int t = 0; t < T_HE; t++) scL[tid][t] = e[t] * inv;
  }
  __syncthreads();
  {
    int nn = tid >> 5, dq = tid & 31;
    float4 acc = make_float4(0.f, 0.f, 0.f, 0.f);
#pragma unroll
    for (int t = 0; t < T_HE; t++) {
      float sw = scL[nn][t];
      float4 xv = *(const float4*)&xL[nn][t][dq << 2];
      acc.x = fmaf(sw, xv.x, acc.x);
      acc.y = fmaf(sw, xv.y, acc.y);
      acc.z = fmaf(sw, xv.z, acc.z);
      acc.w = fmaf(sw, xv.w, acc.w);
    }
    *(float4*)&aggL[nn][dq << 2] = acc;
  }
  __syncthreads();
  {
    int dout = tid & 127, g = tid >> 7;
    float a0 = fcb[dout], a1 = a0, a2 = a0, a3 = a0;
    for (int dq = 0; dq < 32; dq++) {
      int db = dq * 4;
      float wv0 = fcw[(db + 0) * 128 + dout];
      float wv1 = fcw[(db + 1) * 128 + dout];
      float wv2 = fcw[(db + 2) * 128 + dout];
      float wv3 = fcw[(db + 3) * 128 + dout];
      float4 v0 = *(const float4*)&aggL[g * 4 + 0][db];
      float4 v1 = *(const float4*)&aggL[g * 4 + 1][db];
      float4 v2 = *(const float4*)&aggL[g * 4 + 2][db];
      float4 v3 = *(const float4*)&aggL[g * 4 + 3][db];
      a0 = fmaf(v0.x, wv0, fmaf(v0.y, wv1, fmaf(v0.z, wv2, fmaf(v0.w, wv3, a0))));
      a1 = fmaf(v1.x, wv0, fmaf(v1.y, wv1, fmaf(v1.z, wv2, fmaf(v1.w, wv3, a1))));
      a2 = fmaf(v2.x, wv0, fmaf(v2.y, wv1, fmaf(v2.z, wv2, fmaf(v2.w, wv3, a2))));
      a3 = fmaf(v3.x, wv0, fmaf(v3.y, wv1, fmaf(v3.z, wv2, fmaf(v3.w, wv3, a3))));
    }
    int nb = n0 + g * 4;
    if (nb + 0 < N_NODES) out[(size_t)(nb + 0) * 128 + dout] = fmaxf(a0, 0.f);
    if (nb + 1 < N_NODES) out[(size_t)(nb + 1) * 128 + dout] = fmaxf(a1, 0.f);
    if (nb + 2 < N_NODES) out[(size_t)(nb + 2) * 128 + dout] = fmaxf(a2, 0.f);
    if (nb + 3 < N_NODES) out[(size_t)(nb + 3) * 128 + dout] = fmaxf(a3, 0.f);
  }
}

extern "C" void kernel_launch(void* const* d_in, const int* in_sizes, int n_in,
                              void* d_out, int out_size, void* d_ws, size_t ws_size,
                              hipStream_t stream) {
  (void)in_sizes; (void)n_in; (void)out_size; (void)ws_size;
  const float* feats       = (const float*)d_in[1];
  const int*   cluster_idx = (const int*)d_in[2];
  const int*   struct_idx  = (const int*)d_in[3];
  const float* wKK_c = (const float*)d_in[5];
  const float* bKK_c = (const float*)d_in[6];
  const float* wK1_c = (const float*)d_in[7];
  const float* bK1_c = (const float*)d_in[8];
  const float* wKK_n = (const float*)d_in[9];
  const float* bKK_n = (const float*)d_in[10];
  const float* wK1_n = (const float*)d_in[11];
  const float* bK1_n = (const float*)d_in[12];
  const float* wKK_s = (const float*)d_in[13];
  const float* bKK_s = (const float*)d_in[14];
  const float* wK1_s = (const float*)d_in[15];
  const float* bK1_s = (const float*)d_in[16];
  const float* ec_w1 = (const float*)d_in[17];
  const float* ec_b1 = (const float*)d_in[18];
  const float* ec_w2 = (const float*)d_in[19];
  const float* ec_b2 = (const float*)d_in[20];
  const float* fc_w  = (const float*)d_in[21];
  const float* fc_b  = (const float*)d_in[22];
  float* out = (float*)d_out;

  // ws layout (lifetime-overlapped, <= 72.32 MB):
  //  [0, 2.56M)         xnh (bf16)
  //  [2.56M, 12.8M)     cand (u32)
  //  [12.8M, 14.08M)    candIdx (int)
  //  [14.08M, 14.16M)   normD (f64)
  //  [14.16M, 16.72M)   fHi (bf16 feats hi)
  //  [16.72M, 19.28M)   fLo (bf16 feats lo)
  //  [19.28M, 19.68M)   wHi (bf16: c|n|s = 32768|32768|131072 shorts)
  //  [19.68M, 20.08M)   wLo
  //  [46.08M, 46.72M)   knn (int)
  //  [46.72M, 72.32M)   hx (f32)
  char* wsb = (char*)d_ws;
  unsigned short* xnh = (unsigned short*)(wsb);
  unsigned* cand = (unsigned*)(wsb + 2560000);
  int* candIdx = (int*)(wsb + 12800000);
  double* normD = (double*)(wsb + 14080000);
  unsigned short* fHi = (unsigned short*)(wsb + 14160000);
  unsigned short* fLo = (unsigned short*)(wsb + 16720000);
  unsigned short* wHi = (unsigned short*)(wsb + 19280000);
  unsigned short* wLo = (unsigned short*)(wsb + 19680000);
  int* knnIdx = (int*)(wsb + 46080000);
  float* hx = (float*)(wsb + 46720000);

  kpre<<<2884, 256, 0, stream>>>(feats, wKK_c, wKK_n, wKK_s,
                                 xnh, fHi, fLo, normD, wHi, wLo);
  ksim<<<dim3(79, NCH), 256, 0, stream>>>(xnh, cand);
  kmerge<<<(N_NODES + 63) / 64, 64, 0, stream>>>(cand, candIdx);
  krerank<<<N_NODES, 256, 0, stream>>>(feats, normD, candIdx, knnIdx);

  kvcall<<<dim3(625, 5), 256, 0, stream>>>(fHi, fLo, cluster_idx, knnIdx, struct_idx,
                                           wHi, wLo, bKK_c, bKK_n, bKK_s,
                                           wK1_c, bK1_c, wK1_n, bK1_n, wK1_s, bK1_s, hx);

  kfinal<<<1250, 256, 0, stream>>>(hx, ec_w1, ec_b1, ec_w2, ec_b2, fc_w, fc_b, out);
}

// Round 12
// 390.566 us; speedup vs baseline: 1.3274x; 1.3274x over previous
//
#include <hip/hip_runtime.h>
#include <cmath>

// DHGLayer on MI355X. N=10000, D=128.
// kpre (normalize -> bf16 xnh for sim; fp16 feats/W tables for vertex conv)
// -> ksim (bf16 MFMA sim + wave-local top-16, R10-proven 110us version) ->
// kmerge -> krerank (f64 exact top-16) -> kvcall (fused vertex conv, all 5
// branches: fp16 MFMA mult + bKK + in-register softmax + fp16 combine) ->
// kfinal (float4 LDS).
// R11 lesson: split-bf16 (hi+lo) made every gathered row 512B and the hot set
// 5.5MB > 4MB per-XCD L2 -> capacity thrash (FETCH 126MB, 818 GB/s, 189us).
// fp16 rows: 256B/row, hot set 3MB (L2-resident), 1 MFMA not 3, and fp16's
// 2^-12 rel error is 8x tighter than bf16 -> output delta ~5e-5, far under
// threshold. f64 rerank keeps knn exact regardless.

#define N_NODES 10000
#define D 128
#define DQ 32
#define NCB 3
#define T_HE 5
#define HID_SZ 32
#define NCH 16
#define CHUNK 625      // 16 * 625 = 10000
#define TOPK 16
#define TOPM 32

typedef __attribute__((ext_vector_type(8))) short short8;
typedef __attribute__((ext_vector_type(8))) _Float16 half8;
typedef __attribute__((ext_vector_type(4))) float f32x4;
typedef __attribute__((ext_vector_type(16))) float f32x16;

// ---------------- helpers ----------------
__device__ __forceinline__ unsigned bf16rne(float f) {
  unsigned u = __float_as_uint(f);
  return (u + 0x7FFFu + ((u >> 16) & 1u)) >> 16;
}

// ---------------- fused prep: bf16 xnh + fp16 feats + fp16 W + f64 norm ----------------
// grid 2884: bx<2500 -> 4 feature rows (64 threads each); else -> W pair chunks.
__global__ __launch_bounds__(256) void kpre(const float* __restrict__ feats,
                                            const float* __restrict__ wc,
                                            const float* __restrict__ wn,
                                            const float* __restrict__ wstr,
                                            unsigned short* __restrict__ xnh,
                                            _Float16* __restrict__ fH16,
                                            double* __restrict__ normD,
                                            _Float16* __restrict__ wH16) {
  int bx = blockIdx.x;
  int tid = threadIdx.x;
  if (bx < 2500) {
    int n = bx * 4 + (tid >> 6);
    int lane = tid & 63;
    float2 v = ((const float2*)(feats + (size_t)n * D))[lane];
    _Float16 p2[2] = {(_Float16)v.x, (_Float16)v.y};
    ((unsigned*)(fH16 + (size_t)n * D))[lane] = *(const unsigned*)p2;
    double ss = (double)v.x * (double)v.x + (double)v.y * (double)v.y;
#pragma unroll
    for (int o = 32; o > 0; o >>= 1) ss += __shfl_xor(ss, o);
    double nd = fmax(sqrt(ss), 1e-12);
    if (lane == 0) normD[n] = nd;
    float inv = (float)(1.0 / nd);
    ((unsigned*)(xnh + (size_t)n * D))[lane] = bf16rne(v.x * inv) | (bf16rne(v.y * inv) << 16);
  } else {
    int p = (bx - 2500) * 256 + tid;
    if (p >= 98304) return;
    int e = p * 2;
    float2 v;
    if (e < 32768) v = *(const float2*)(wc + e);
    else if (e < 65536) v = *(const float2*)(wn + (e - 32768));
    else v = *(const float2*)(wstr + (e - 65536));
    _Float16 p2[2] = {(_Float16)v.x, (_Float16)v.y};
    ((unsigned*)wH16)[p] = *(const unsigned*)p2;
  }
}

// ---------------- sorting-network helpers ----------------
__device__ __forceinline__ void ceu(unsigned& a, unsigned& b) {
  unsigned lo = min(a, b), hi = max(a, b);
  a = lo; b = hi;
}
__device__ __forceinline__ void ceu64(unsigned long long& a, unsigned long long& b) {
  unsigned long long lo = min(a, b), hi = max(a, b);
  a = lo; b = hi;
}
__device__ __forceinline__ void sort16_asc(unsigned (&v)[16]) {
#pragma unroll
  for (int k = 2; k <= 16; k <<= 1) {
#pragma unroll
    for (int j = k >> 1; j > 0; j >>= 1) {
#pragma unroll
      for (int i = 0; i < 16; i++) {
        int x = i ^ j;
        if (x > i) {
          if ((i & k) == 0) ceu(v[i], v[x]);
          else ceu(v[x], v[i]);
        }
      }
    }
  }
}
__device__ __forceinline__ void merge16_asc(unsigned (&run)[16], const unsigned (&b)[16]) {
  unsigned m[16];
#pragma unroll
  for (int i = 0; i < 16; i++) m[i] = max(run[i], b[15 - i]);
#pragma unroll
  for (int j = 8; j > 0; j >>= 1) {
#pragma unroll
    for (int i = 0; i < 16; i++) {
      if ((i & j) == 0) ceu(m[i], m[i + j]);
    }
  }
#pragma unroll
  for (int i = 0; i < 16; i++) run[i] = m[i];
}

// ---------------- bf16 MFMA sim + per-chunk top-16 (R10-proven, 110us) ----------------
__global__ __launch_bounds__(256, 3) void ksim(const unsigned short* __restrict__ xnh,
                                               unsigned* __restrict__ cand) {
  __shared__ short Bb[16 * 128 * 8];    // [kp][ci][8 bf16] = 32 KB
  __shared__ unsigned kb[4][32 * 35];   // per-wave private, 17.5 KB
  int tid = threadIdx.x;
  int w = tid >> 6, lane = tid & 63, l31 = lane & 31, lh = lane >> 5;
  int row0 = blockIdx.x * 128 + w * 32;
  int chunk = blockIdx.y;
  int cbase = chunk * CHUNK;

  short8 afr[8];
  {
    int ar = min(row0 + l31, N_NODES - 1);
    const short8* ap = (const short8*)(xnh + (size_t)ar * D);
#pragma unroll
    for (int ks = 0; ks < 8; ks++) afr[ks] = ap[ks * 2 + lh];
  }

  unsigned run[16];
#pragma unroll
  for (int s = 0; s < 16; s++) run[s] = 0u;
  unsigned* kbw = kb[w];
  int srow = lane >> 1, soff = (lane & 1) * 16;

  for (int ti = 0; ti < 5; ti++) {
    int tb = cbase + ti * 128;
    __syncthreads();
    {
      int ci = tid >> 1, h = tid & 1;
      int gcol = min(tb + ci, N_NODES - 1);
      const short8* gp = (const short8*)(xnh + (size_t)gcol * D);
      short8* bp = (short8*)Bb;
#pragma unroll
      for (int i = 0; i < 8; i++) bp[(h * 8 + i) * 128 + ci] = gp[h * 8 + i];
    }
    __syncthreads();

    f32x16 acc[4];
#pragma unroll
    for (int ni = 0; ni < 4; ni++)
#pragma unroll
      for (int r = 0; r < 16; r++) acc[ni][r] = 0.f;
    const short8* bv = (const short8*)Bb;
#pragma unroll
    for (int ks = 0; ks < 8; ks++) {
      int kp = ks * 2 + lh;
#pragma unroll
      for (int ni = 0; ni < 4; ni++) {
        short8 bf = bv[kp * 128 + ni * 32 + l31];
        acc[ni] = __builtin_amdgcn_mfma_f32_32x32x16_bf16(afr[ks], bf, acc[ni], 0, 0, 0);
      }
    }

#pragma unroll
    for (int ni = 0; ni < 4; ni++) {
      int cb2 = ti * 128 + ni * 32;
#pragma unroll
      for (int reg = 0; reg < 16; reg++) {
        int r = (reg & 3) + 8 * (reg >> 2) + 4 * lh;
        int cic = cb2 + l31;
        unsigned bb = __float_as_uint(acc[ni][reg]);
        unsigned mu = (bb & 0x80000000u) ? ~bb : (bb | 0x80000000u);
        unsigned key = (cic < CHUNK) ? ((mu & 0xFFFFFC00u) | (unsigned)(1023 - cic)) : 0u;
        kbw[r * 35 + l31] = key;
      }
      unsigned bt[16];
      const unsigned* rp = &kbw[srow * 35 + soff];
#pragma unroll
      for (int q = 0; q < 4; q++) {
        uint4 t4 = *(const uint4*)(rp + q * 4);
        bt[q * 4 + 0] = t4.x; bt[q * 4 + 1] = t4.y;
        bt[q * 4 + 2] = t4.z; bt[q * 4 + 3] = t4.w;
      }
      sort16_asc(bt);
      merge16_asc(run, bt);
    }
  }
  {
    unsigned other[16];
#pragma unroll
    for (int s = 0; s < 16; s++) other[s] = (unsigned)__shfl_xor((int)run[s], 1);
    merge16_asc(run, other);
  }
  int grow = row0 + srow;
  if ((lane & 1) == 0 && grow < N_NODES) {
    unsigned* o = cand + ((size_t)grow * NCH + chunk) * 16;
#pragma unroll
    for (int i = 0; i < 16; i += 4)
      *(uint4*)(o + i) = make_uint4(run[i], run[i + 1], run[i + 2], run[i + 3]);
  }
}

// ---------------- merge chunk keys -> top-32 candidate cols ----------------
__global__ __launch_bounds__(64) void kmerge(const unsigned* __restrict__ cand,
                                             int* __restrict__ candIdx) {
  int row = blockIdx.x * 64 + threadIdx.x;
  if (row >= N_NODES) return;
  unsigned long long run[TOPM];
#pragma unroll
  for (int s = 0; s < TOPM; s++) run[s] = 0ull;
  const uint4* c4 = (const uint4*)(cand + (size_t)row * (NCH * 16));
  for (int ch = 0; ch < NCH; ch++) {
    unsigned b[16];
#pragma unroll
    for (int q = 0; q < 4; q++) {
      uint4 t = c4[ch * 4 + q];
      b[q * 4 + 0] = t.x; b[q * 4 + 1] = t.y;
      b[q * 4 + 2] = t.z; b[q * 4 + 3] = t.w;
    }
    unsigned base = (unsigned)(ch * CHUNK);
    unsigned long long b64[16];
#pragma unroll
    for (int s = 0; s < 16; s++) {
      unsigned k = b[s];
      unsigned gcol = base + (1023u - (k & 1023u));
      b64[s] = ((unsigned long long)(k >> 10) << 32) | (unsigned long long)(~gcol);
    }
#pragma unroll
    for (int i = 0; i < 16; i++) run[i] = max(run[i], b64[15 - i]);
#pragma unroll
    for (int j = 16; j > 0; j >>= 1)
#pragma unroll
      for (int i = 0; i < TOPM; i++)
        if ((i & j) == 0) ceu64(run[i], run[i + j]);
  }
  int4* o4 = (int4*)(candIdx + (size_t)row * TOPM);
#pragma unroll
  for (int s = 0; s < TOPM; s += 4) {
    int4 o;
    o.x = (int)(~(unsigned)(run[s + 0] & 0xFFFFFFFFull));
    o.y = (int)(~(unsigned)(run[s + 1] & 0xFFFFFFFFull));
    o.z = (int)(~(unsigned)(run[s + 2] & 0xFFFFFFFFull));
    o.w = (int)(~(unsigned)(run[s + 3] & 0xFFFFFFFFull));
    o4[s >> 2] = o;
  }
}

// ---------------- f64 exact re-rank of 32 candidates -> knn top-16 ----------------
__global__ __launch_bounds__(256) void krerank(const float* __restrict__ feats,
                                               const double* __restrict__ normD,
                                               const int* __restrict__ candIdx,
                                               int* __restrict__ knn) {
  __shared__ float rowF[D];
  __shared__ double simL[TOPM];
  __shared__ int idxL[TOPM];
  int row = blockIdx.x;
  int tid = threadIdx.x;
  if (tid < DQ)
    ((float4*)rowF)[tid] = ((const float4*)(feats + (size_t)row * D))[tid];
  int c = tid >> 3, part = tid & 7;
  int cnd = candIdx[(size_t)row * TOPM + c];
  __syncthreads();
  const float4* f4 = (const float4*)(feats + (size_t)cnd * D);
  double acc = 0.0;
#pragma unroll
  for (int g = 0; g < 4; g++) {
    float4 v = f4[part * 4 + g];
    const float* rf = &rowF[(part * 4 + g) * 4];
    acc = fma((double)v.x, (double)rf[0], acc);
    acc = fma((double)v.y, (double)rf[1], acc);
    acc = fma((double)v.z, (double)rf[2], acc);
    acc = fma((double)v.w, (double)rf[3], acc);
  }
  acc += __shfl_down(acc, 4);
  acc += __shfl_down(acc, 2);
  acc += __shfl_down(acc, 1);
  if (part == 0) {
    simL[c] = acc / (normD[row] * normD[cnd]);
    idxL[c] = cnd;
  }
  __syncthreads();
  if (tid < TOPM) {
    double s = simL[tid];
    int idx = idxL[tid];
    int rank = 0;
#pragma unroll
    for (int o = 0; o < TOPM; o++) {
      double so = simL[o];
      int io = idxL[o];
      rank += (so > s || (so == s && io < idx)) ? 1 : 0;
    }
    if (rank < TOPK) knn[(size_t)row * TOPK + rank] = idx;
  }
}

// ---------------- FUSED vertex conv, all 5 branches (fp16) ----------------
// grid (625, 5), 256 thr = 4 waves, 16 nodes/block. Waves split the i-loop.
// fp16 MFMA mult (1 mfma/kc) + bKK + shfl softmax; partial coef -> LDS ->
// reduce -> fp16 combine. Hot set fH16 2.56MB + wH16 0.4MB: per-XCD L2
// resident (vs R11 split-bf16 5.5MB thrash -> FETCH 126MB, 189us).
__global__ __launch_bounds__(256) void kvcall(
    const _Float16* __restrict__ fH16,
    const int* __restrict__ cluster_idx, const int* __restrict__ knn,
    const int* __restrict__ struct_idx,
    const _Float16* __restrict__ wH16,
    const float* __restrict__ bKK_c, const float* __restrict__ bKK_n,
    const float* __restrict__ bKK_s,
    const float* __restrict__ wK1_c, const float* __restrict__ bK1_c,
    const float* __restrict__ wK1_n, const float* __restrict__ bK1_n,
    const float* __restrict__ wK1_s, const float* __restrict__ bK1_s,
    float* __restrict__ hx) {
  __shared__ int idxL[16][33];
  __shared__ float coefP[4][16][33];
  __shared__ float coefS[16][33];
  int tid = threadIdx.x;
  int z = blockIdx.y;
  int n0 = blockIdx.x * 16;             // 625*16 = 10000 exactly
  int w = tid >> 6, lane = tid & 63, l15 = lane & 15, quad = lane >> 4;
  const half8* fH = (const half8*)fH16;   // 16 half8 per row

  if (z < 4) {
    // ---------------- K = 16 ----------------
    const int* idxTab; int istr, ioff, woff;
    const float* bKK; const float* wK1; const float* bK1p;
    if (z < 3) { idxTab = cluster_idx; istr = NCB * 16; ioff = z * 16; woff = 0;     bKK = bKK_c; wK1 = wK1_c; bK1p = bK1_c; }
    else       { idxTab = knn;         istr = 16;       ioff = 0;      woff = 32768; bKK = bKK_n; wK1 = wK1_n; bK1p = bK1_n; }
    {
      int nn = tid >> 4, i = tid & 15;
      idxL[nn][i] = idxTab[(size_t)(n0 + nn) * istr + ioff + i];
    }
    __syncthreads();
    const half8* wHv = (const half8*)(wH16 + woff);
    f32x4 coef = {0.f, 0.f, 0.f, 0.f};
#pragma unroll
    for (int ii = 0; ii < 4; ii++) {
      int i = w * 4 + ii;
      int rowi = idxL[l15][i];
      float bkk = bKK[i * 16 + l15];
      f32x4 acc = {0.f, 0.f, 0.f, 0.f};
#pragma unroll
      for (int kc = 0; kc < 4; kc++) {
        half8 ah = fH[(size_t)rowi * 16 + kc * 4 + quad];
        half8 bh = wHv[((size_t)i * 16 + l15) * 16 + kc * 4 + quad];
        acc = __builtin_amdgcn_mfma_f32_16x16x32_f16(ah, bh, acc, 0, 0, 0);
      }
      float wki = wK1[i];
#pragma unroll
      for (int r = 0; r < 4; r++) {
        float v = acc[r] + bkk;
        float mx = v;
#pragma unroll
        for (int msk = 1; msk < 16; msk <<= 1) mx = fmaxf(mx, __shfl_xor(mx, msk));
        float e = __expf(v - mx);
        float s = e;
#pragma unroll
        for (int msk = 1; msk < 16; msk <<= 1) s += __shfl_xor(s, msk);
        coef[r] += wki * (e / s);
      }
    }
#pragma unroll
    for (int r = 0; r < 4; r++) coefP[w][quad * 4 + r][l15] = coef[r];
    __syncthreads();
    {
      int nn = tid >> 4, j = tid & 15;
      coefS[nn][j] = coefP[0][nn][j] + coefP[1][nn][j] + coefP[2][nn][j] + coefP[3][nn][j];
    }
    __syncthreads();
    {
      int nl = tid >> 4, g = tid & 15;
      float bk1 = bK1p[0];
      float a8[8];
#pragma unroll
      for (int t = 0; t < 8; t++) a8[t] = bk1;
      for (int j = 0; j < 16; j++) {
        float cf = coefS[nl][j];
        int rowj = idxL[nl][j];
        half8 xv = fH[(size_t)rowj * 16 + g];   // dims g*8..g*8+7
#pragma unroll
        for (int e = 0; e < 8; e++) a8[e] = fmaf(cf, (float)xv[e], a8[e]);
      }
      int node = n0 + nl;
      float4* o = (float4*)(hx + ((size_t)node * T_HE + z) * D + g * 8);
      o[0] = make_float4(a8[0], a8[1], a8[2], a8[3]);
      o[1] = make_float4(a8[4], a8[5], a8[6], a8[7]);
    }
  } else {
    // ---------------- K = 32 (struct) ----------------
    for (int e = tid; e < 512; e += 256) {
      int nn = e >> 5, i = e & 31;
      idxL[nn][i] = struct_idx[(size_t)(n0 + nn) * 32 + i];
    }
    __syncthreads();
    const half8* wHv = (const half8*)(wH16 + 65536);
    f32x4 coef0 = {0.f, 0.f, 0.f, 0.f};
    f32x4 coef1 = {0.f, 0.f, 0.f, 0.f};
#pragma unroll
    for (int ii = 0; ii < 8; ii++) {
      int i = w * 8 + ii;
      int rowi = idxL[l15][i];
      float bk0 = bKK_s[i * 32 + l15];
      float bk1v = bKK_s[i * 32 + 16 + l15];
      f32x4 a0 = {0.f, 0.f, 0.f, 0.f};
      f32x4 a1 = {0.f, 0.f, 0.f, 0.f};
#pragma unroll
      for (int kc = 0; kc < 4; kc++) {
        half8 ah = fH[(size_t)rowi * 16 + kc * 4 + quad];
        half8 b0 = wHv[((size_t)i * 32 + l15) * 16 + kc * 4 + quad];
        half8 b1 = wHv[((size_t)i * 32 + 16 + l15) * 16 + kc * 4 + quad];
        a0 = __builtin_amdgcn_mfma_f32_16x16x32_f16(ah, b0, a0, 0, 0, 0);
        a1 = __builtin_amdgcn_mfma_f32_16x16x32_f16(ah, b1, a1, 0, 0, 0);
      }
      float wki = wK1_s[i];
#pragma unroll
      for (int r = 0; r < 4; r++) {
        float v0 = a0[r] + bk0, v1 = a1[r] + bk1v;
        float mx = fmaxf(v0, v1);
#pragma unroll
        for (int msk = 1; msk < 16; msk <<= 1) mx = fmaxf(mx, __shfl_xor(mx, msk));
        float e0 = __expf(v0 - mx), e1 = __expf(v1 - mx);
        float s = e0 + e1;
#pragma unroll
        for (int msk = 1; msk < 16; msk <<= 1) s += __shfl_xor(s, msk);
        float inv = wki / s;
        coef0[r] += e0 * inv;
        coef1[r] += e1 * inv;
      }
    }
#pragma unroll
    for (int r = 0; r < 4; r++) {
      coefP[w][quad * 4 + r][l15] = coef0[r];
      coefP[w][quad * 4 + r][l15 + 16] = coef1[r];
    }
    __syncthreads();
    for (int e = tid; e < 512; e += 256) {
      int nn = e >> 5, j = e & 31;
      coefS[nn][j] = coefP[0][nn][j] + coefP[1][nn][j] + coefP[2][nn][j] + coefP[3][nn][j];
    }
    __syncthreads();
    {
      int nl = tid >> 4, g = tid & 15;
      float bk1 = bK1_s[0];
      float a8[8];
#pragma unroll
      for (int t = 0; t < 8; t++) a8[t] = bk1;
      for (int j = 0; j < 32; j++) {
        float cf = coefS[nl][j];
        int rowj = idxL[nl][j];
        half8 xv = fH[(size_t)rowj * 16 + g];
#pragma unroll
        for (int e = 0; e < 8; e++) a8[e] = fmaf(cf, (float)xv[e], a8[e]);
      }
      int node = n0 + nl;
      float4* o = (float4*)(hx + ((size_t)node * T_HE + 4) * D + g * 8);
      o[0] = make_float4(a8[0], a8[1], a8[2], a8[3]);
      o[1] = make_float4(a8[4], a8[5], a8[6], a8[7]);
    }
  }
}

// ---------------- edge attention + fc (float4 LDS) ----------------
__global__ __launch_bounds__(256) void kfinal(const float* __restrict__ hx,
    const float* __restrict__ w1, const float* __restrict__ b1,
    const float* __restrict__ w2, const float* __restrict__ b2p,
    const float* __restrict__ fcw, const float* __restrict__ fcb,
    float* __restrict__ out) {
  __shared__ float xL[8][T_HE][D];
  __shared__ float hL[8][T_HE][HID_SZ];
  __shared__ float scL[8][T_HE];
  __shared__ float aggL[8][D];
  int tid = threadIdx.x;
  int n0 = blockIdx.x * 8;
  const float4* hx4 = (const float4*)hx;
  for (int q = tid; q < 8 * T_HE * DQ; q += 256) {
    int nn = q / (T_HE * DQ);
    int rem = q - nn * (T_HE * DQ);
    int t = rem / DQ;
    int dq = rem & 31;
    int node = n0 + nn;
    float4 val = make_float4(0.f, 0.f, 0.f, 0.f);
    if (node < N_NODES) val = hx4[((size_t)node * T_HE + t) * DQ + dq];
    *(float4*)&xL[nn][t][dq << 2] = val;
  }
  __syncthreads();
  for (int q = tid; q < 8 * T_HE * HID_SZ; q += 256) {
    int nn = q / (T_HE * HID_SZ);
    int rem = q - nn * (T_HE * HID_SZ);
    int t = rem / HID_SZ;
    int hh = rem & (HID_SZ - 1);
    float acc = b1[hh];
    const float4* xv4 = (const float4*)xL[nn][t];
    for (int dq = 0; dq < 32; dq++) {
      float4 xv = xv4[dq];
      int db = dq * 4;
      acc = fmaf(xv.x, w1[(db + 0) * HID_SZ + hh], acc);
      acc = fmaf(xv.y, w1[(db + 1) * HID_SZ + hh], acc);
      acc = fmaf(xv.z, w1[(db + 2) * HID_SZ + hh], acc);
      acc = fmaf(xv.w, w1[(db + 3) * HID_SZ + hh], acc);
    }
    hL[nn][t][hh] = fmaxf(acc, 0.f);
  }
  __syncthreads();
  if (tid < 8 * T_HE) {
    int nn = tid / T_HE, t = tid % T_HE;
    float acc = b2p[0];
    for (int hh = 0; hh < HID_SZ; hh++) acc = fmaf(hL[nn][t][hh], w2[hh], acc);
    scL[nn][t] = acc;
  }
  __syncthreads();
  if (tid < 8) {
    float mx = -1e30f;
#pragma unroll
    for (int t = 0; t < T_HE; t++) mx = fmaxf(mx, scL[tid][t]);
    float e[T_HE];
    float s = 0.f;
#pragma unroll
    for (int t = 0; t < T_HE; t++) { e[t] = expf(scL[tid][t] - mx); s += e[t]; }
    float inv = 1.f / s;
#pragma unroll
    for (int t = 0; t < T_HE; t++) scL[tid][t] = e[t] * inv;
  }
  __syncthreads();
  {
    int nn = tid >> 5, dq = tid & 31;
    float4 acc = make_float4(0.f, 0.f, 0.f, 0.f);
#pragma unroll
    for (int t = 0; t < T_HE; t++) {
      float sw = scL[nn][t];
      float4 xv = *(const float4*)&xL[nn][t][dq << 2];
      acc.x = fmaf(sw, xv.x, acc.x);
      acc.y = fmaf(sw, xv.y, acc.y);
      acc.z = fmaf(sw, xv.z, acc.z);
      acc.w = fmaf(sw, xv.w, acc.w);
    }
    *(float4*)&aggL[nn][dq << 2] = acc;
  }
  __syncthreads();
  {
    int dout = tid & 127, g = tid >> 7;
    float a0 = fcb[dout], a1 = a0, a2 = a0, a3 = a0;
    for (int dq = 0; dq < 32; dq++) {
      int db = dq * 4;
      float wv0 = fcw[(db + 0) * 128 + dout];
      float wv1 = fcw[(db + 1) * 128 + dout];
      float wv2 = fcw[(db + 2) * 128 + dout];
      float wv3 = fcw[(db + 3) * 128 + dout];
      float4 v0 = *(const float4*)&aggL[g * 4 + 0][db];
      float4 v1 = *(const float4*)&aggL[g * 4 + 1][db];
      float4 v2 = *(const float4*)&aggL[g * 4 + 2][db];
      float4 v3 = *(const float4*)&aggL[g * 4 + 3][db];
      a0 = fmaf(v0.x, wv0, fmaf(v0.y, wv1, fmaf(v0.z, wv2, fmaf(v0.w, wv3, a0))));
      a1 = fmaf(v1.x, wv0, fmaf(v1.y, wv1, fmaf(v1.z, wv2, fmaf(v1.w, wv3, a1))));
      a2 = fmaf(v2.x, wv0, fmaf(v2.y, wv1, fmaf(v2.z, wv2, fmaf(v2.w, wv3, a2))));
      a3 = fmaf(v3.x, wv0, fmaf(v3.y, wv1, fmaf(v3.z, wv2, fmaf(v3.w, wv3, a3))));
    }
    int nb = n0 + g * 4;
    if (nb + 0 < N_NODES) out[(size_t)(nb + 0) * 128 + dout] = fmaxf(a0, 0.f);
    if (nb + 1 < N_NODES) out[(size_t)(nb + 1) * 128 + dout] = fmaxf(a1, 0.f);
    if (nb + 2 < N_NODES) out[(size_t)(nb + 2) * 128 + dout] = fmaxf(a2, 0.f);
    if (nb + 3 < N_NODES) out[(size_t)(nb + 3) * 128 + dout] = fmaxf(a3, 0.f);
  }
}

extern "C" void kernel_launch(void* const* d_in, const int* in_sizes, int n_in,
                              void* d_out, int out_size, void* d_ws, size_t ws_size,
                              hipStream_t stream) {
  (void)in_sizes; (void)n_in; (void)out_size; (void)ws_size;
  const float* feats       = (const float*)d_in[1];
  const int*   cluster_idx = (const int*)d_in[2];
  const int*   struct_idx  = (const int*)d_in[3];
  const float* wKK_c = (const float*)d_in[5];
  const float* bKK_c = (const float*)d_in[6];
  const float* wK1_c = (const float*)d_in[7];
  const float* bK1_c = (const float*)d_in[8];
  const float* wKK_n = (const float*)d_in[9];
  const float* bKK_n = (const float*)d_in[10];
  const float* wK1_n = (const float*)d_in[11];
  const float* bK1_n = (const float*)d_in[12];
  const float* wKK_s = (const float*)d_in[13];
  const float* bKK_s = (const float*)d_in[14];
  const float* wK1_s = (const float*)d_in[15];
  const float* bK1_s = (const float*)d_in[16];
  const float* ec_w1 = (const float*)d_in[17];
  const float* ec_b1 = (const float*)d_in[18];
  const float* ec_w2 = (const float*)d_in[19];
  const float* ec_b2 = (const float*)d_in[20];
  const float* fc_w  = (const float*)d_in[21];
  const float* fc_b  = (const float*)d_in[22];
  float* out = (float*)d_out;

  // ws layout (lifetime-overlapped, <= 72.32 MB):
  //  [0, 2.56M)         xnh (bf16)
  //  [2.56M, 12.8M)     cand (u32)
  //  [12.8M, 14.08M)    candIdx (int)
  //  [14.08M, 14.16M)   normD (f64)
  //  [14.16M, 16.72M)   fH16 (fp16 feats, 2.56 MB)
  //  [16.72M, 17.12M)   wH16 (fp16 W: c|n|s = 32768|32768|131072 halves)
  //  [46.08M, 46.72M)   knn (int)
  //  [46.72M, 72.32M)   hx (f32)
  char* wsb = (char*)d_ws;
  unsigned short* xnh = (unsigned short*)(wsb);
  unsigned* cand = (unsigned*)(wsb + 2560000);
  int* candIdx = (int*)(wsb + 12800000);
  double* normD = (double*)(wsb + 14080000);
  _Float16* fH16 = (_Float16*)(wsb + 14160000);
  _Float16* wH16 = (_Float16*)(wsb + 16720000);
  int* knnIdx = (int*)(wsb + 46080000);
  float* hx = (float*)(wsb + 46720000);

  kpre<<<2884, 256, 0, stream>>>(feats, wKK_c, wKK_n, wKK_s,
                                 xnh, fH16, normD, wH16);
  ksim<<<dim3(79, NCH), 256, 0, stream>>>(xnh, cand);
  kmerge<<<(N_NODES + 63) / 64, 64, 0, stream>>>(cand, candIdx);
  krerank<<<N_NODES, 256, 0, stream>>>(feats, normD, candIdx, knnIdx);

  kvcall<<<dim3(625, 5), 256, 0, stream>>>(fH16, cluster_idx, knnIdx, struct_idx,
                                           wH16, bKK_c, bKK_n, bKK_s,
                                           wK1_c, bK1_c, wK1_n, bK1_n, wK1_s, bK1_s, hx);

  kfinal<<<1250, 256, 0, stream>>>(hx, ec_w1, ec_b1, ec_w2, ec_b2, fc_w, fc_b, out);
}

// Round 13
// 375.736 us; speedup vs baseline: 1.3797x; 1.0395x over previous
//
#include <hip/hip_runtime.h>
#include <cmath>

// DHGLayer on MI355X. N=10000, D=128.
// kpre (normalize -> bf16 xnh; fp16 feats/W) -> ksim (bf16 MFMA sim with
// SWAPPED operands so each lane's top-16 scan runs on its own row's keys
// directly from MFMA registers -- no LDS keybuf/transpose) -> kmerge ->
// krerank (f64 exact top-16) -> kvcall (fp16 fused vertex conv) -> kfinal.
// R12 lesson: ksim pinned at ~111us across 4 variants; scan's acc->LDS->reg
// transpose cost 2e8 LDS ops + 1.6M conflict cyc + 17.9KB LDS (2 blk/CU).
// sim is SYMMETRIC: mfma(staged_cols_as_A, rows_as_B) puts row = lane&31,
// 16 cols = 16 C/D regs (m74/m101 layout) -> scan entirely in registers,
// lh-halves = the 2 scan lanes/row, final merge shfl_xor(32). LDS 32KB ->
// 4 blk/CU; acc split into 2 passes of 2 col-subtiles to keep VGPR <= 128.

#define N_NODES 10000
#define D 128
#define DQ 32
#define NCB 3
#define T_HE 5
#define HID_SZ 32
#define NCH 16
#define CHUNK 625      // 16 * 625 = 10000
#define TOPK 16
#define TOPM 32

typedef __attribute__((ext_vector_type(8))) short short8;
typedef __attribute__((ext_vector_type(8))) _Float16 half8;
typedef __attribute__((ext_vector_type(4))) float f32x4;
typedef __attribute__((ext_vector_type(16))) float f32x16;

// ---------------- helpers ----------------
__device__ __forceinline__ unsigned bf16rne(float f) {
  unsigned u = __float_as_uint(f);
  return (u + 0x7FFFu + ((u >> 16) & 1u)) >> 16;
}

// ---------------- fused prep: bf16 xnh + fp16 feats + fp16 W + f64 norm ----------------
__global__ __launch_bounds__(256) void kpre(const float* __restrict__ feats,
                                            const float* __restrict__ wc,
                                            const float* __restrict__ wn,
                                            const float* __restrict__ wstr,
                                            unsigned short* __restrict__ xnh,
                                            _Float16* __restrict__ fH16,
                                            double* __restrict__ normD,
                                            _Float16* __restrict__ wH16) {
  int bx = blockIdx.x;
  int tid = threadIdx.x;
  if (bx < 2500) {
    int n = bx * 4 + (tid >> 6);
    int lane = tid & 63;
    float2 v = ((const float2*)(feats + (size_t)n * D))[lane];
    _Float16 p2[2] = {(_Float16)v.x, (_Float16)v.y};
    ((unsigned*)(fH16 + (size_t)n * D))[lane] = *(const unsigned*)p2;
    double ss = (double)v.x * (double)v.x + (double)v.y * (double)v.y;
#pragma unroll
    for (int o = 32; o > 0; o >>= 1) ss += __shfl_xor(ss, o);
    double nd = fmax(sqrt(ss), 1e-12);
    if (lane == 0) normD[n] = nd;
    float inv = (float)(1.0 / nd);
    ((unsigned*)(xnh + (size_t)n * D))[lane] = bf16rne(v.x * inv) | (bf16rne(v.y * inv) << 16);
  } else {
    int p = (bx - 2500) * 256 + tid;
    if (p >= 98304) return;
    int e = p * 2;
    float2 v;
    if (e < 32768) v = *(const float2*)(wc + e);
    else if (e < 65536) v = *(const float2*)(wn + (e - 32768));
    else v = *(const float2*)(wstr + (e - 65536));
    _Float16 p2[2] = {(_Float16)v.x, (_Float16)v.y};
    ((unsigned*)wH16)[p] = *(const unsigned*)p2;
  }
}

// ---------------- sorting-network helpers ----------------
__device__ __forceinline__ void ceu(unsigned& a, unsigned& b) {
  unsigned lo = min(a, b), hi = max(a, b);
  a = lo; b = hi;
}
__device__ __forceinline__ void ceu64(unsigned long long& a, unsigned long long& b) {
  unsigned long long lo = min(a, b), hi = max(a, b);
  a = lo; b = hi;
}
__device__ __forceinline__ void sort16_asc(unsigned (&v)[16]) {
#pragma unroll
  for (int k = 2; k <= 16; k <<= 1) {
#pragma unroll
    for (int j = k >> 1; j > 0; j >>= 1) {
#pragma unroll
      for (int i = 0; i < 16; i++) {
        int x = i ^ j;
        if (x > i) {
          if ((i & k) == 0) ceu(v[i], v[x]);
          else ceu(v[x], v[i]);
        }
      }
    }
  }
}
__device__ __forceinline__ void merge16_asc(unsigned (&run)[16], const unsigned (&b)[16]) {
  unsigned m[16];
#pragma unroll
  for (int i = 0; i < 16; i++) m[i] = max(run[i], b[15 - i]);
#pragma unroll
  for (int j = 8; j > 0; j >>= 1) {
#pragma unroll
    for (int i = 0; i < 16; i++) {
      if ((i & j) == 0) ceu(m[i], m[i + j]);
    }
  }
#pragma unroll
  for (int i = 0; i < 16; i++) run[i] = m[i];
}

// ---------------- bf16 MFMA sim + in-register per-chunk top-16 ----------------
// grid (79 row-blocks of 128, 16 chunks of 625). 4 waves; wave w owns rows
// w*32..+31. Operands SWAPPED: A = staged candidate cols (m = l31 within
// sub-tile), B = afr rows (n = l31). C/D: n(lane&31) = our row, m(regs) =
// candidate col => keys packed straight from acc regs. 2 passes of 2
// col-subtiles keep live acc at 32 VGPRs. lh-halves hold disjoint 16-col
// slices of the same row; final merge via shfl_xor(32). LDS = Bb 32KB only.
__global__ __launch_bounds__(256, 4) void ksim(const unsigned short* __restrict__ xnh,
                                               unsigned* __restrict__ cand) {
  __shared__ short Bb[16 * 128 * 8];    // [kp][ci][8 bf16] = 32 KB
  int tid = threadIdx.x;
  int w = tid >> 6, lane = tid & 63, l31 = lane & 31, lh = lane >> 5;
  int row0 = blockIdx.x * 128 + w * 32;
  int chunk = blockIdx.y;
  int cbase = chunk * CHUNK;

  short8 afr[8];   // B operand: n = l31 (our row), k = ks*16 + lh*8
  {
    int ar = min(row0 + l31, N_NODES - 1);
    const short8* ap = (const short8*)(xnh + (size_t)ar * D);
#pragma unroll
    for (int ks = 0; ks < 8; ks++) afr[ks] = ap[ks * 2 + lh];
  }

  unsigned run[16];
#pragma unroll
  for (int s = 0; s < 16; s++) run[s] = 0u;

  for (int ti = 0; ti < 5; ti++) {
    int tb = cbase + ti * 128;
    __syncthreads();
    {  // stage B-tile (cols tb..tb+127) k-major; fully coalesced
      int ci = tid >> 1, h = tid & 1;
      int gcol = min(tb + ci, N_NODES - 1);
      const short8* gp = (const short8*)(xnh + (size_t)gcol * D);
      short8* bp = (short8*)Bb;
#pragma unroll
      for (int i = 0; i < 8; i++) bp[(h * 8 + i) * 128 + ci] = gp[h * 8 + i];
    }
    __syncthreads();

    const short8* bv = (const short8*)Bb;
#pragma unroll
    for (int half = 0; half < 2; half++) {
      f32x16 acc[2];
#pragma unroll
      for (int nj = 0; nj < 2; nj++)
#pragma unroll
        for (int r = 0; r < 16; r++) acc[nj][r] = 0.f;
#pragma unroll
      for (int ks = 0; ks < 8; ks++) {
        int kp = ks * 2 + lh;
#pragma unroll
        for (int nj = 0; nj < 2; nj++) {
          int ni = half * 2 + nj;
          short8 af = bv[kp * 128 + ni * 32 + l31];   // A: m = l31 (cand col)
          acc[nj] = __builtin_amdgcn_mfma_f32_32x32x16_bf16(af, afr[ks], acc[nj], 0, 0, 0);
        }
      }
      // scan: keys straight from acc regs (m = (reg&3)+8*(reg>>2)+4*lh)
#pragma unroll
      for (int nj = 0; nj < 2; nj++) {
        int ni = half * 2 + nj;
        unsigned bt[16];
#pragma unroll
        for (int reg = 0; reg < 16; reg++) {
          int m = (reg & 3) + 8 * (reg >> 2) + 4 * lh;
          int cic = ti * 128 + ni * 32 + m;
          unsigned bb = __float_as_uint(acc[nj][reg]);
          unsigned mu = (bb & 0x80000000u) ? ~bb : (bb | 0x80000000u);
          bt[reg] = (cic < CHUNK) ? ((mu & 0xFFFFFC00u) | (unsigned)(1023 - cic)) : 0u;
        }
        sort16_asc(bt);
        merge16_asc(run, bt);
      }
    }
  }
  // lane-half merge: (l31, lh=0) and (l31, lh=1) hold disjoint col-slices
  {
    unsigned other[16];
#pragma unroll
    for (int s = 0; s < 16; s++) other[s] = (unsigned)__shfl_xor((int)run[s], 32);
    merge16_asc(run, other);
  }
  int grow = row0 + l31;
  if (lh == 0 && grow < N_NODES) {
    unsigned* o = cand + ((size_t)grow * NCH + chunk) * 16;
#pragma unroll
    for (int i = 0; i < 16; i += 4)
      *(uint4*)(o + i) = make_uint4(run[i], run[i + 1], run[i + 2], run[i + 3]);
  }
}

// ---------------- merge chunk keys -> top-32 candidate cols ----------------
__global__ __launch_bounds__(64) void kmerge(const unsigned* __restrict__ cand,
                                             int* __restrict__ candIdx) {
  int row = blockIdx.x * 64 + threadIdx.x;
  if (row >= N_NODES) return;
  unsigned long long run[TOPM];
#pragma unroll
  for (int s = 0; s < TOPM; s++) run[s] = 0ull;
  const uint4* c4 = (const uint4*)(cand + (size_t)row * (NCH * 16));
  for (int ch = 0; ch < NCH; ch++) {
    unsigned b[16];
#pragma unroll
    for (int q = 0; q < 4; q++) {
      uint4 t = c4[ch * 4 + q];
      b[q * 4 + 0] = t.x; b[q * 4 + 1] = t.y;
      b[q * 4 + 2] = t.z; b[q * 4 + 3] = t.w;
    }
    unsigned base = (unsigned)(ch * CHUNK);
    unsigned long long b64[16];
#pragma unroll
    for (int s = 0; s < 16; s++) {
      unsigned k = b[s];
      unsigned gcol = base + (1023u - (k & 1023u));
      b64[s] = ((unsigned long long)(k >> 10) << 32) | (unsigned long long)(~gcol);
    }
#pragma unroll
    for (int i = 0; i < 16; i++) run[i] = max(run[i], b64[15 - i]);
#pragma unroll
    for (int j = 16; j > 0; j >>= 1)
#pragma unroll
      for (int i = 0; i < TOPM; i++)
        if ((i & j) == 0) ceu64(run[i], run[i + j]);
  }
  int4* o4 = (int4*)(candIdx + (size_t)row * TOPM);
#pragma unroll
  for (int s = 0; s < TOPM; s += 4) {
    int4 o;
    o.x = (int)(~(unsigned)(run[s + 0] & 0xFFFFFFFFull));
    o.y = (int)(~(unsigned)(run[s + 1] & 0xFFFFFFFFull));
    o.z = (int)(~(unsigned)(run[s + 2] & 0xFFFFFFFFull));
    o.w = (int)(~(unsigned)(run[s + 3] & 0xFFFFFFFFull));
    o4[s >> 2] = o;
  }
}

// ---------------- f64 exact re-rank of 32 candidates -> knn top-16 ----------------
__global__ __launch_bounds__(256) void krerank(const float* __restrict__ feats,
                                               const double* __restrict__ normD,
                                               const int* __restrict__ candIdx,
                                               int* __restrict__ knn) {
  __shared__ float rowF[D];
  __shared__ double simL[TOPM];
  __shared__ int idxL[TOPM];
  int row = blockIdx.x;
  int tid = threadIdx.x;
  if (tid < DQ)
    ((float4*)rowF)[tid] = ((const float4*)(feats + (size_t)row * D))[tid];
  int c = tid >> 3, part = tid & 7;
  int cnd = candIdx[(size_t)row * TOPM + c];
  __syncthreads();
  const float4* f4 = (const float4*)(feats + (size_t)cnd * D);
  double acc = 0.0;
#pragma unroll
  for (int g = 0; g < 4; g++) {
    float4 v = f4[part * 4 + g];
    const float* rf = &rowF[(part * 4 + g) * 4];
    acc = fma((double)v.x, (double)rf[0], acc);
    acc = fma((double)v.y, (double)rf[1], acc);
    acc = fma((double)v.z, (double)rf[2], acc);
    acc = fma((double)v.w, (double)rf[3], acc);
  }
  acc += __shfl_down(acc, 4);
  acc += __shfl_down(acc, 2);
  acc += __shfl_down(acc, 1);
  if (part == 0) {
    simL[c] = acc / (normD[row] * normD[cnd]);
    idxL[c] = cnd;
  }
  __syncthreads();
  if (tid < TOPM) {
    double s = simL[tid];
    int idx = idxL[tid];
    int rank = 0;
#pragma unroll
    for (int o = 0; o < TOPM; o++) {
      double so = simL[o];
      int io = idxL[o];
      rank += (so > s || (so == s && io < idx)) ? 1 : 0;
    }
    if (rank < TOPK) knn[(size_t)row * TOPK + rank] = idx;
  }
}

// ---------------- FUSED vertex conv, all 5 branches (fp16) ----------------
__global__ __launch_bounds__(256) void kvcall(
    const _Float16* __restrict__ fH16,
    const int* __restrict__ cluster_idx, const int* __restrict__ knn,
    const int* __restrict__ struct_idx,
    const _Float16* __restrict__ wH16,
    const float* __restrict__ bKK_c, const float* __restrict__ bKK_n,
    const float* __restrict__ bKK_s,
    const float* __restrict__ wK1_c, const float* __restrict__ bK1_c,
    const float* __restrict__ wK1_n, const float* __restrict__ bK1_n,
    const float* __restrict__ wK1_s, const float* __restrict__ bK1_s,
    float* __restrict__ hx) {
  __shared__ int idxL[16][33];
  __shared__ float coefP[4][16][33];
  __shared__ float coefS[16][33];
  int tid = threadIdx.x;
  int z = blockIdx.y;
  int n0 = blockIdx.x * 16;             // 625*16 = 10000 exactly
  int w = tid >> 6, lane = tid & 63, l15 = lane & 15, quad = lane >> 4;
  const half8* fH = (const half8*)fH16;   // 16 half8 per row

  if (z < 4) {
    // ---------------- K = 16 ----------------
    const int* idxTab; int istr, ioff, woff;
    const float* bKK; const float* wK1; const float* bK1p;
    if (z < 3) { idxTab = cluster_idx; istr = NCB * 16; ioff = z * 16; woff = 0;     bKK = bKK_c; wK1 = wK1_c; bK1p = bK1_c; }
    else       { idxTab = knn;         istr = 16;       ioff = 0;      woff = 32768; bKK = bKK_n; wK1 = wK1_n; bK1p = bK1_n; }
    {
      int nn = tid >> 4, i = tid & 15;
      idxL[nn][i] = idxTab[(size_t)(n0 + nn) * istr + ioff + i];
    }
    __syncthreads();
    const half8* wHv = (const half8*)(wH16 + woff);
    f32x4 coef = {0.f, 0.f, 0.f, 0.f};
#pragma unroll
    for (int ii = 0; ii < 4; ii++) {
      int i = w * 4 + ii;
      int rowi = idxL[l15][i];
      float bkk = bKK[i * 16 + l15];
      f32x4 acc = {0.f, 0.f, 0.f, 0.f};
#pragma unroll
      for (int kc = 0; kc < 4; kc++) {
        half8 ah = fH[(size_t)rowi * 16 + kc * 4 + quad];
        half8 bh = wHv[((size_t)i * 16 + l15) * 16 + kc * 4 + quad];
        acc = __builtin_amdgcn_mfma_f32_16x16x32_f16(ah, bh, acc, 0, 0, 0);
      }
      float wki = wK1[i];
#pragma unroll
      for (int r = 0; r < 4; r++) {
        float v = acc[r] + bkk;
        float mx = v;
#pragma unroll
        for (int msk = 1; msk < 16; msk <<= 1) mx = fmaxf(mx, __shfl_xor(mx, msk));
        float e = __expf(v - mx);
        float s = e;
#pragma unroll
        for (int msk = 1; msk < 16; msk <<= 1) s += __shfl_xor(s, msk);
        coef[r] += wki * (e / s);
      }
    }
#pragma unroll
    for (int r = 0; r < 4; r++) coefP[w][quad * 4 + r][l15] = coef[r];
    __syncthreads();
    {
      int nn = tid >> 4, j = tid & 15;
      coefS[nn][j] = coefP[0][nn][j] + coefP[1][nn][j] + coefP[2][nn][j] + coefP[3][nn][j];
    }
    __syncthreads();
    {
      int nl = tid >> 4, g = tid & 15;
      float bk1 = bK1p[0];
      float a8[8];
#pragma unroll
      for (int t = 0; t < 8; t++) a8[t] = bk1;
      for (int j = 0; j < 16; j++) {
        float cf = coefS[nl][j];
        int rowj = idxL[nl][j];
        half8 xv = fH[(size_t)rowj * 16 + g];   // dims g*8..g*8+7
#pragma unroll
        for (int e = 0; e < 8; e++) a8[e] = fmaf(cf, (float)xv[e], a8[e]);
      }
      int node = n0 + nl;
      float4* o = (float4*)(hx + ((size_t)node * T_HE + z) * D + g * 8);
      o[0] = make_float4(a8[0], a8[1], a8[2], a8[3]);
      o[1] = make_float4(a8[4], a8[5], a8[6], a8[7]);
    }
  } else {
    // ---------------- K = 32 (struct) ----------------
    for (int e = tid; e < 512; e += 256) {
      int nn = e >> 5, i = e & 31;
      idxL[nn][i] = struct_idx[(size_t)(n0 + nn) * 32 + i];
    }
    __syncthreads();
    const half8* wHv = (const half8*)(wH16 + 65536);
    f32x4 coef0 = {0.f, 0.f, 0.f, 0.f};
    f32x4 coef1 = {0.f, 0.f, 0.f, 0.f};
#pragma unroll
    for (int ii = 0; ii < 8; ii++) {
      int i = w * 8 + ii;
      int rowi = idxL[l15][i];
      float bk0 = bKK_s[i * 32 + l15];
      float bk1v = bKK_s[i * 32 + 16 + l15];
      f32x4 a0 = {0.f, 0.f, 0.f, 0.f};
      f32x4 a1 = {0.f, 0.f, 0.f, 0.f};
#pragma unroll
      for (int kc = 0; kc < 4; kc++) {
        half8 ah = fH[(size_t)rowi * 16 + kc * 4 + quad];
        half8 b0 = wHv[((size_t)i * 32 + l15) * 16 + kc * 4 + quad];
        half8 b1 = wHv[((size_t)i * 32 + 16 + l15) * 16 + kc * 4 + quad];
        a0 = __builtin_amdgcn_mfma_f32_16x16x32_f16(ah, b0, a0, 0, 0, 0);
        a1 = __builtin_amdgcn_mfma_f32_16x16x32_f16(ah, b1, a1, 0, 0, 0);
      }
      float wki = wK1_s[i];
#pragma unroll
      for (int r = 0; r < 4; r++) {
        float v0 = a0[r] + bk0, v1 = a1[r] + bk1v;
        float mx = fmaxf(v0, v1);
#pragma unroll
        for (int msk = 1; msk < 16; msk <<= 1) mx = fmaxf(mx, __shfl_xor(mx, msk));
        float e0 = __expf(v0 - mx), e1 = __expf(v1 - mx);
        float s = e0 + e1;
#pragma unroll
        for (int msk = 1; msk < 16; msk <<= 1) s += __shfl_xor(s, msk);
        float inv = wki / s;
        coef0[r] += e0 * inv;
        coef1[r] += e1 * inv;
      }
    }
#pragma unroll
    for (int r = 0; r < 4; r++) {
      coefP[w][quad * 4 + r][l15] = coef0[r];
      coefP[w][quad * 4 + r][l15 + 16] = coef1[r];
    }
    __syncthreads();
    for (int e = tid; e < 512; e += 256) {
      int nn = e >> 5, j = e & 31;
      coefS[nn][j] = coefP[0][nn][j] + coefP[1][nn][j] + coefP[2][nn][j] + coefP[3][nn][j];
    }
    __syncthreads();
    {
      int nl = tid >> 4, g = tid & 15;
      float bk1 = bK1_s[0];
      float a8[8];
#pragma unroll
      for (int t = 0; t < 8; t++) a8[t] = bk1;
      for (int j = 0; j < 32; j++) {
        float cf = coefS[nl][j];
        int rowj = idxL[nl][j];
        half8 xv = fH[(size_t)rowj * 16 + g];
#pragma unroll
        for (int e = 0; e < 8; e++) a8[e] = fmaf(cf, (float)xv[e], a8[e]);
      }
      int node = n0 + nl;
      float4* o = (float4*)(hx + ((size_t)node * T_HE + 4) * D + g * 8);
      o[0] = make_float4(a8[0], a8[1], a8[2], a8[3]);
      o[1] = make_float4(a8[4], a8[5], a8[6], a8[7]);
    }
  }
}

// ---------------- edge attention + fc (float4 LDS) ----------------
__global__ __launch_bounds__(256) void kfinal(const float* __restrict__ hx,
    const float* __restrict__ w1, const float* __restrict__ b1,
    const float* __restrict__ w2, const float* __restrict__ b2p,
    const float* __restrict__ fcw, const float* __restrict__ fcb,
    float* __restrict__ out) {
  __shared__ float xL[8][T_HE][D];
  __shared__ float hL[8][T_HE][HID_SZ];
  __shared__ float scL[8][T_HE];
  __shared__ float aggL[8][D];
  int tid = threadIdx.x;
  int n0 = blockIdx.x * 8;
  const float4* hx4 = (const float4*)hx;
  for (int q = tid; q < 8 * T_HE * DQ; q += 256) {
    int nn = q / (T_HE * DQ);
    int rem = q - nn * (T_HE * DQ);
    int t = rem / DQ;
    int dq = rem & 31;
    int node = n0 + nn;
    float4 val = make_float4(0.f, 0.f, 0.f, 0.f);
    if (node < N_NODES) val = hx4[((size_t)node * T_HE + t) * DQ + dq];
    *(float4*)&xL[nn][t][dq << 2] = val;
  }
  __syncthreads();
  for (int q = tid; q < 8 * T_HE * HID_SZ; q += 256) {
    int nn = q / (T_HE * HID_SZ);
    int rem = q - nn * (T_HE * HID_SZ);
    int t = rem / HID_SZ;
    int hh = rem & (HID_SZ - 1);
    float acc = b1[hh];
    const float4* xv4 = (const float4*)xL[nn][t];
    for (int dq = 0; dq < 32; dq++) {
      float4 xv = xv4[dq];
      int db = dq * 4;
      acc = fmaf(xv.x, w1[(db + 0) * HID_SZ + hh], acc);
      acc = fmaf(xv.y, w1[(db + 1) * HID_SZ + hh], acc);
      acc = fmaf(xv.z, w1[(db + 2) * HID_SZ + hh], acc);
      acc = fmaf(xv.w, w1[(db + 3) * HID_SZ + hh], acc);
    }
    hL[nn][t][hh] = fmaxf(acc, 0.f);
  }
  __syncthreads();
  if (tid < 8 * T_HE) {
    int nn = tid / T_HE, t = tid % T_HE;
    float acc = b2p[0];
    for (int hh = 0; hh < HID_SZ; hh++) acc = fmaf(hL[nn][t][hh], w2[hh], acc);
    scL[nn][t] = acc;
  }
  __syncthreads();
  if (tid < 8) {
    float mx = -1e30f;
#pragma unroll
    for (int t = 0; t < T_HE; t++) mx = fmaxf(mx, scL[tid][t]);
    float e[T_HE];
    float s = 0.f;
#pragma unroll
    for (int t = 0; t < T_HE; t++) { e[t] = expf(scL[tid][t] - mx); s += e[t]; }
    float inv = 1.f / s;
#pragma unroll
    for (int t = 0; t < T_HE; t++) scL[tid][t] = e[t] * inv;
  }
  __syncthreads();
  {
    int nn = tid >> 5, dq = tid & 31;
    float4 acc = make_float4(0.f, 0.f, 0.f, 0.f);
#pragma unroll
    for (int t = 0; t < T_HE; t++) {
      float sw = scL[nn][t];
      float4 xv = *(const float4*)&xL[nn][t][dq << 2];
      acc.x = fmaf(sw, xv.x, acc.x);
      acc.y = fmaf(sw, xv.y, acc.y);
      acc.z = fmaf(sw, xv.z, acc.z);
      acc.w = fmaf(sw, xv.w, acc.w);
    }
    *(float4*)&aggL[nn][dq << 2] = acc;
  }
  __syncthreads();
  {
    int dout = tid & 127, g = tid >> 7;
    float a0 = fcb[dout], a1 = a0, a2 = a0, a3 = a0;
    for (int dq = 0; dq < 32; dq++) {
      int db = dq * 4;
      float wv0 = fcw[(db + 0) * 128 + dout];
      float wv1 = fcw[(db + 1) * 128 + dout];
      float wv2 = fcw[(db + 2) * 128 + dout];
      float wv3 = fcw[(db + 3) * 128 + dout];
      float4 v0 = *(const float4*)&aggL[g * 4 + 0][db];
      float4 v1 = *(const float4*)&aggL[g * 4 + 1][db];
      float4 v2 = *(const float4*)&aggL[g * 4 + 2][db];
      float4 v3 = *(const float4*)&aggL[g * 4 + 3][db];
      a0 = fmaf(v0.x, wv0, fmaf(v0.y, wv1, fmaf(v0.z, wv2, fmaf(v0.w, wv3, a0))));
      a1 = fmaf(v1.x, wv0, fmaf(v1.y, wv1, fmaf(v1.z, wv2, fmaf(v1.w, wv3, a1))));
      a2 = fmaf(v2.x, wv0, fmaf(v2.y, wv1, fmaf(v2.z, wv2, fmaf(v2.w, wv3, a2))));
      a3 = fmaf(v3.x, wv0, fmaf(v3.y, wv1, fmaf(v3.z, wv2, fmaf(v3.w, wv3, a3))));
    }
    int nb = n0 + g * 4;
    if (nb + 0 < N_NODES) out[(size_t)(nb + 0) * 128 + dout] = fmaxf(a0, 0.f);
    if (nb + 1 < N_NODES) out[(size_t)(nb + 1) * 128 + dout] = fmaxf(a1, 0.f);
    if (nb + 2 < N_NODES) out[(size_t)(nb + 2) * 128 + dout] = fmaxf(a2, 0.f);
    if (nb + 3 < N_NODES) out[(size_t)(nb + 3) * 128 + dout] = fmaxf(a3, 0.f);
  }
}

extern "C" void kernel_launch(void* const* d_in, const int* in_sizes, int n_in,
                              void* d_out, int out_size, void* d_ws, size_t ws_size,
                              hipStream_t stream) {
  (void)in_sizes; (void)n_in; (void)out_size; (void)ws_size;
  const float* feats       = (const float*)d_in[1];
  const int*   cluster_idx = (const int*)d_in[2];
  const int*   struct_idx  = (const int*)d_in[3];
  const float* wKK_c = (const float*)d_in[5];
  const float* bKK_c = (const float*)d_in[6];
  const float* wK1_c = (const float*)d_in[7];
  const float* bK1_c = (const float*)d_in[8];
  const float* wKK_n = (const float*)d_in[9];
  const float* bKK_n = (const float*)d_in[10];
  const float* wK1_n = (const float*)d_in[11];
  const float* bK1_n = (const float*)d_in[12];
  const float* wKK_s = (const float*)d_in[13];
  const float* bKK_s = (const float*)d_in[14];
  const float* wK1_s = (const float*)d_in[15];
  const float* bK1_s = (const float*)d_in[16];
  const float* ec_w1 = (const float*)d_in[17];
  const float* ec_b1 = (const float*)d_in[18];
  const float* ec_w2 = (const float*)d_in[19];
  const float* ec_b2 = (const float*)d_in[20];
  const float* fc_w  = (const float*)d_in[21];
  const float* fc_b  = (const float*)d_in[22];
  float* out = (float*)d_out;

  // ws layout (lifetime-overlapped, <= 72.32 MB):
  //  [0, 2.56M)         xnh (bf16)
  //  [2.56M, 12.8M)     cand (u32)
  //  [12.8M, 14.08M)    candIdx (int)
  //  [14.08M, 14.16M)   normD (f64)
  //  [14.16M, 16.72M)   fH16 (fp16 feats, 2.56 MB)
  //  [16.72M, 17.12M)   wH16 (fp16 W: c|n|s = 32768|32768|131072 halves)
  //  [46.08M, 46.72M)   knn (int)
  //  [46.72M, 72.32M)   hx (f32)
  char* wsb = (char*)d_ws;
  unsigned short* xnh = (unsigned short*)(wsb);
  unsigned* cand = (unsigned*)(wsb + 2560000);
  int* candIdx = (int*)(wsb + 12800000);
  double* normD = (double*)(wsb + 14080000);
  _Float16* fH16 = (_Float16*)(wsb + 14160000);
  _Float16* wH16 = (_Float16*)(wsb + 16720000);
  int* knnIdx = (int*)(wsb + 46080000);
  float* hx = (float*)(wsb + 46720000);

  kpre<<<2884, 256, 0, stream>>>(feats, wKK_c, wKK_n, wKK_s,
                                 xnh, fH16, normD, wH16);
  ksim<<<dim3(79, NCH), 256, 0, stream>>>(xnh, cand);
  kmerge<<<(N_NODES + 63) / 64, 64, 0, stream>>>(cand, candIdx);
  krerank<<<N_NODES, 256, 0, stream>>>(feats, normD, candIdx, knnIdx);

  kvcall<<<dim3(625, 5), 256, 0, stream>>>(fH16, cluster_idx, knnIdx, struct_idx,
                                           wH16, bKK_c, bKK_n, bKK_s,
                                           wK1_c, bK1_c, wK1_n, bK1_n, wK1_s, bK1_s, hx);

  kfinal<<<1250, 256, 0, stream>>>(hx, ec_w1, ec_b1, ec_w2, ec_b2, fc_w, fc_b, out);
}

// Round 14
// 364.870 us; speedup vs baseline: 1.4208x; 1.0298x over previous
//
#include <hip/hip_runtime.h>
#include <cmath>

// DHGLayer on MI355X. N=10000, D=128.
// kpre (normalize -> bf16 xnh; fp16 feats/W) -> ksimvc (MEGA: bf16 MFMA sim
// with in-register top-16 scan INTERLEAVED 1:2 with the 4 knn-independent
// vertex-conv branches: cluster x3 + struct) -> kmerge -> krerank (f64 exact
// top-16) -> kvc3 (knn vertex conv) -> kfinal.
// R13 lesson: ksim is VALU-dependency-bound (57% VALU, occupancy limited by
// block SUPPLY at 4.9 blk/CU, not resources); 43% of its cycles are idle
// mem/MFMA slots. kvcall (~60-90us, gather-heavy, VALU-light, and independent
// of the sim chain for z != knn) co-schedules into those slots (m114: waves on
// different pipes overlap ~max not sum). Interleave 1 sim : 2 vc blocks so CUs
// hold ~3 sim (32KB LDS) + ~5 vc (12.7KB) concurrently.

#define N_NODES 10000
#define D 128
#define DQ 32
#define NCB 3
#define T_HE 5
#define HID_SZ 32
#define NCH 16
#define CHUNK 625      // 16 * 625 = 10000
#define TOPK 16
#define TOPM 32

typedef __attribute__((ext_vector_type(8))) short short8;
typedef __attribute__((ext_vector_type(8))) _Float16 half8;
typedef __attribute__((ext_vector_type(4))) float f32x4;
typedef __attribute__((ext_vector_type(16))) float f32x16;

// ---------------- helpers ----------------
__device__ __forceinline__ unsigned bf16rne(float f) {
  unsigned u = __float_as_uint(f);
  return (u + 0x7FFFu + ((u >> 16) & 1u)) >> 16;
}

// ---------------- fused prep: bf16 xnh + fp16 feats + fp16 W + f64 norm ----------------
__global__ __launch_bounds__(256) void kpre(const float* __restrict__ feats,
                                            const float* __restrict__ wc,
                                            const float* __restrict__ wn,
                                            const float* __restrict__ wstr,
                                            unsigned short* __restrict__ xnh,
                                            _Float16* __restrict__ fH16,
                                            double* __restrict__ normD,
                                            _Float16* __restrict__ wH16) {
  int bx = blockIdx.x;
  int tid = threadIdx.x;
  if (bx < 2500) {
    int n = bx * 4 + (tid >> 6);
    int lane = tid & 63;
    float2 v = ((const float2*)(feats + (size_t)n * D))[lane];
    _Float16 p2[2] = {(_Float16)v.x, (_Float16)v.y};
    ((unsigned*)(fH16 + (size_t)n * D))[lane] = *(const unsigned*)p2;
    double ss = (double)v.x * (double)v.x + (double)v.y * (double)v.y;
#pragma unroll
    for (int o = 32; o > 0; o >>= 1) ss += __shfl_xor(ss, o);
    double nd = fmax(sqrt(ss), 1e-12);
    if (lane == 0) normD[n] = nd;
    float inv = (float)(1.0 / nd);
    ((unsigned*)(xnh + (size_t)n * D))[lane] = bf16rne(v.x * inv) | (bf16rne(v.y * inv) << 16);
  } else {
    int p = (bx - 2500) * 256 + tid;
    if (p >= 98304) return;
    int e = p * 2;
    float2 v;
    if (e < 32768) v = *(const float2*)(wc + e);
    else if (e < 65536) v = *(const float2*)(wn + (e - 32768));
    else v = *(const float2*)(wstr + (e - 65536));
    _Float16 p2[2] = {(_Float16)v.x, (_Float16)v.y};
    ((unsigned*)wH16)[p] = *(const unsigned*)p2;
  }
}

// ---------------- sorting-network helpers ----------------
__device__ __forceinline__ void ceu(unsigned& a, unsigned& b) {
  unsigned lo = min(a, b), hi = max(a, b);
  a = lo; b = hi;
}
__device__ __forceinline__ void ceu64(unsigned long long& a, unsigned long long& b) {
  unsigned long long lo = min(a, b), hi = max(a, b);
  a = lo; b = hi;
}
__device__ __forceinline__ void sort16_asc(unsigned (&v)[16]) {
#pragma unroll
  for (int k = 2; k <= 16; k <<= 1) {
#pragma unroll
    for (int j = k >> 1; j > 0; j >>= 1) {
#pragma unroll
      for (int i = 0; i < 16; i++) {
        int x = i ^ j;
        if (x > i) {
          if ((i & k) == 0) ceu(v[i], v[x]);
          else ceu(v[x], v[i]);
        }
      }
    }
  }
}
__device__ __forceinline__ void merge16_asc(unsigned (&run)[16], const unsigned (&b)[16]) {
  unsigned m[16];
#pragma unroll
  for (int i = 0; i < 16; i++) m[i] = max(run[i], b[15 - i]);
#pragma unroll
  for (int j = 8; j > 0; j >>= 1) {
#pragma unroll
    for (int i = 0; i < 16; i++) {
      if ((i & j) == 0) ceu(m[i], m[i + j]);
    }
  }
#pragma unroll
  for (int i = 0; i < 16; i++) run[i] = m[i];
}

// ---------------- vertex-conv device bodies (shared LDS via pointers) ----------------
// LDS layout in smem: idxL (16x33 int, 2112B) | coefP (4x16x33 f32, 8448B) |
// coefS (16x33 f32, 2112B) = 12672B.
__device__ __forceinline__ void vc16_body(int tid, int n0, int tslot,
    int* idxLm, float* coefPm, float* coefSm,
    const _Float16* __restrict__ fH16, const _Float16* __restrict__ wH16,
    const int* __restrict__ idxTab, int istr, int ioff, int woff,
    const float* __restrict__ bKK, const float* __restrict__ wK1,
    const float* __restrict__ bK1p, float* __restrict__ hx) {
  int w = tid >> 6, lane = tid & 63, l15 = lane & 15, quad = lane >> 4;
  const half8* fH = (const half8*)fH16;
  {
    int nn = tid >> 4, i = tid & 15;
    idxLm[nn * 33 + i] = idxTab[(size_t)(n0 + nn) * istr + ioff + i];
  }
  __syncthreads();
  const half8* wHv = (const half8*)(wH16 + woff);
  f32x4 coef = {0.f, 0.f, 0.f, 0.f};
#pragma unroll
  for (int ii = 0; ii < 4; ii++) {
    int i = w * 4 + ii;
    int rowi = idxLm[l15 * 33 + i];
    float bkk = bKK[i * 16 + l15];
    f32x4 acc = {0.f, 0.f, 0.f, 0.f};
#pragma unroll
    for (int kc = 0; kc < 4; kc++) {
      half8 ah = fH[(size_t)rowi * 16 + kc * 4 + quad];
      half8 bh = wHv[((size_t)i * 16 + l15) * 16 + kc * 4 + quad];
      acc = __builtin_amdgcn_mfma_f32_16x16x32_f16(ah, bh, acc, 0, 0, 0);
    }
    float wki = wK1[i];
#pragma unroll
    for (int r = 0; r < 4; r++) {
      float v = acc[r] + bkk;
      float mx = v;
#pragma unroll
      for (int msk = 1; msk < 16; msk <<= 1) mx = fmaxf(mx, __shfl_xor(mx, msk));
      float e = __expf(v - mx);
      float s = e;
#pragma unroll
      for (int msk = 1; msk < 16; msk <<= 1) s += __shfl_xor(s, msk);
      coef[r] += wki * (e / s);
    }
  }
#pragma unroll
  for (int r = 0; r < 4; r++) coefPm[(w * 16 + quad * 4 + r) * 33 + l15] = coef[r];
  __syncthreads();
  {
    int nn = tid >> 4, j = tid & 15;
    coefSm[nn * 33 + j] = coefPm[(nn) * 33 + j] + coefPm[(16 + nn) * 33 + j] +
                          coefPm[(32 + nn) * 33 + j] + coefPm[(48 + nn) * 33 + j];
  }
  __syncthreads();
  {
    int nl = tid >> 4, g = tid & 15;
    float bk1 = bK1p[0];
    float a8[8];
#pragma unroll
    for (int t = 0; t < 8; t++) a8[t] = bk1;
    for (int j = 0; j < 16; j++) {
      float cf = coefSm[nl * 33 + j];
      int rowj = idxLm[nl * 33 + j];
      half8 xv = fH[(size_t)rowj * 16 + g];
#pragma unroll
      for (int e = 0; e < 8; e++) a8[e] = fmaf(cf, (float)xv[e], a8[e]);
    }
    int node = n0 + nl;
    float4* o = (float4*)(hx + ((size_t)node * T_HE + tslot) * D + g * 8);
    o[0] = make_float4(a8[0], a8[1], a8[2], a8[3]);
    o[1] = make_float4(a8[4], a8[5], a8[6], a8[7]);
  }
}

__device__ __forceinline__ void vc32_body(int tid, int n0,
    int* idxLm, float* coefPm, float* coefSm,
    const _Float16* __restrict__ fH16, const _Float16* __restrict__ wH16,
    const int* __restrict__ struct_idx,
    const float* __restrict__ bKK_s, const float* __restrict__ wK1_s,
    const float* __restrict__ bK1_s, float* __restrict__ hx) {
  int w = tid >> 6, lane = tid & 63, l15 = lane & 15, quad = lane >> 4;
  const half8* fH = (const half8*)fH16;
  for (int e = tid; e < 512; e += 256) {
    int nn = e >> 5, i = e & 31;
    idxLm[nn * 33 + i] = struct_idx[(size_t)(n0 + nn) * 32 + i];
  }
  __syncthreads();
  const half8* wHv = (const half8*)(wH16 + 65536);
  f32x4 coef0 = {0.f, 0.f, 0.f, 0.f};
  f32x4 coef1 = {0.f, 0.f, 0.f, 0.f};
#pragma unroll
  for (int ii = 0; ii < 8; ii++) {
    int i = w * 8 + ii;
    int rowi = idxLm[l15 * 33 + i];
    float bk0 = bKK_s[i * 32 + l15];
    float bk1v = bKK_s[i * 32 + 16 + l15];
    f32x4 a0 = {0.f, 0.f, 0.f, 0.f};
    f32x4 a1 = {0.f, 0.f, 0.f, 0.f};
#pragma unroll
    for (int kc = 0; kc < 4; kc++) {
      half8 ah = fH[(size_t)rowi * 16 + kc * 4 + quad];
      half8 b0 = wHv[((size_t)i * 32 + l15) * 16 + kc * 4 + quad];
      half8 b1 = wHv[((size_t)i * 32 + 16 + l15) * 16 + kc * 4 + quad];
      a0 = __builtin_amdgcn_mfma_f32_16x16x32_f16(ah, b0, a0, 0, 0, 0);
      a1 = __builtin_amdgcn_mfma_f32_16x16x32_f16(ah, b1, a1, 0, 0, 0);
    }
    float wki = wK1_s[i];
#pragma unroll
    for (int r = 0; r < 4; r++) {
      float v0 = a0[r] + bk0, v1 = a1[r] + bk1v;
      float mx = fmaxf(v0, v1);
#pragma unroll
      for (int msk = 1; msk < 16; msk <<= 1) mx = fmaxf(mx, __shfl_xor(mx, msk));
      float e0 = __expf(v0 - mx), e1 = __expf(v1 - mx);
      float s = e0 + e1;
#pragma unroll
      for (int msk = 1; msk < 16; msk <<= 1) s += __shfl_xor(s, msk);
      float inv = wki / s;
      coef0[r] += e0 * inv;
      coef1[r] += e1 * inv;
    }
  }
#pragma unroll
  for (int r = 0; r < 4; r++) {
    coefPm[(w * 16 + quad * 4 + r) * 33 + l15] = coef0[r];
    coefPm[(w * 16 + quad * 4 + r) * 33 + l15 + 16] = coef1[r];
  }
  __syncthreads();
  for (int e = tid; e < 512; e += 256) {
    int nn = e >> 5, j = e & 31;
    coefSm[nn * 33 + j] = coefPm[nn * 33 + j] + coefPm[(16 + nn) * 33 + j] +
                          coefPm[(32 + nn) * 33 + j] + coefPm[(48 + nn) * 33 + j];
  }
  __syncthreads();
  {
    int nl = tid >> 4, g = tid & 15;
    float bk1 = bK1_s[0];
    float a8[8];
#pragma unroll
    for (int t = 0; t < 8; t++) a8[t] = bk1;
    for (int j = 0; j < 32; j++) {
      float cf = coefSm[nl * 33 + j];
      int rowj = idxLm[nl * 33 + j];
      half8 xv = fH[(size_t)rowj * 16 + g];
#pragma unroll
      for (int e = 0; e < 8; e++) a8[e] = fmaf(cf, (float)xv[e], a8[e]);
    }
    int node = n0 + nl;
    float4* o = (float4*)(hx + ((size_t)node * T_HE + 4) * D + g * 8);
    o[0] = make_float4(a8[0], a8[1], a8[2], a8[3]);
    o[1] = make_float4(a8[4], a8[5], a8[6], a8[7]);
  }
}

// ---------------- MEGA: bf16 MFMA sim (in-register top-16) + vc branches 0,1,2,struct ----------------
// grid 3792, interleave: bx%3==0 -> sim block sid=bx/3 (1264: rb=sid%79,
// chunk=sid/79); else vc block vid=(bx/3)*2+(bx%3-1) (2500 used: zz=vid/625,
// bi=vid%625; zz 0..2 = cluster, 3 = struct). Union LDS 32KB.
__global__ __launch_bounds__(256, 4) void ksimvc(
    const unsigned short* __restrict__ xnh, unsigned* __restrict__ cand,
    const _Float16* __restrict__ fH16, const _Float16* __restrict__ wH16,
    const int* __restrict__ cluster_idx, const int* __restrict__ struct_idx,
    const float* __restrict__ bKK_c, const float* __restrict__ bKK_s,
    const float* __restrict__ wK1_c, const float* __restrict__ bK1_c,
    const float* __restrict__ wK1_s, const float* __restrict__ bK1_s,
    float* __restrict__ hx) {
  __shared__ __align__(16) unsigned char smem[32768];
  int bx = blockIdx.x;
  int tid = threadIdx.x;
  int r3 = bx % 3, q3 = bx / 3;
  if (r3 == 0) {
    // ---------------- sim ----------------
    short* Bb = (short*)smem;
    int rb = q3 % 79, chunk = q3 / 79;
    int w = tid >> 6, lane = tid & 63, l31 = lane & 31, lh = lane >> 5;
    int row0 = rb * 128 + w * 32;
    int cbase = chunk * CHUNK;

    short8 afr[8];   // B operand: n = l31 (our row), k = ks*16 + lh*8
    {
      int ar = min(row0 + l31, N_NODES - 1);
      const short8* ap = (const short8*)(xnh + (size_t)ar * D);
#pragma unroll
      for (int ks = 0; ks < 8; ks++) afr[ks] = ap[ks * 2 + lh];
    }

    unsigned run[16];
#pragma unroll
    for (int s = 0; s < 16; s++) run[s] = 0u;

    for (int ti = 0; ti < 5; ti++) {
      int tb = cbase + ti * 128;
      __syncthreads();
      {  // stage B-tile (cols tb..tb+127) k-major; fully coalesced
        int ci = tid >> 1, h = tid & 1;
        int gcol = min(tb + ci, N_NODES - 1);
        const short8* gp = (const short8*)(xnh + (size_t)gcol * D);
        short8* bp = (short8*)Bb;
#pragma unroll
        for (int i = 0; i < 8; i++) bp[(h * 8 + i) * 128 + ci] = gp[h * 8 + i];
      }
      __syncthreads();

      const short8* bv = (const short8*)Bb;
#pragma unroll
      for (int half = 0; half < 2; half++) {
        f32x16 acc[2];
#pragma unroll
        for (int nj = 0; nj < 2; nj++)
#pragma unroll
          for (int r = 0; r < 16; r++) acc[nj][r] = 0.f;
#pragma unroll
        for (int ks = 0; ks < 8; ks++) {
          int kp = ks * 2 + lh;
#pragma unroll
          for (int nj = 0; nj < 2; nj++) {
            int ni = half * 2 + nj;
            short8 af = bv[kp * 128 + ni * 32 + l31];   // A: m = l31 (cand col)
            acc[nj] = __builtin_amdgcn_mfma_f32_32x32x16_bf16(af, afr[ks], acc[nj], 0, 0, 0);
          }
        }
#pragma unroll
        for (int nj = 0; nj < 2; nj++) {
          int ni = half * 2 + nj;
          unsigned bt[16];
#pragma unroll
          for (int reg = 0; reg < 16; reg++) {
            int m = (reg & 3) + 8 * (reg >> 2) + 4 * lh;
            int cic = ti * 128 + ni * 32 + m;
            unsigned bb = __float_as_uint(acc[nj][reg]);
            unsigned mu = (bb & 0x80000000u) ? ~bb : (bb | 0x80000000u);
            bt[reg] = (cic < CHUNK) ? ((mu & 0xFFFFFC00u) | (unsigned)(1023 - cic)) : 0u;
          }
          sort16_asc(bt);
          merge16_asc(run, bt);
        }
      }
    }
    {
      unsigned other[16];
#pragma unroll
      for (int s = 0; s < 16; s++) other[s] = (unsigned)__shfl_xor((int)run[s], 32);
      merge16_asc(run, other);
    }
    int grow = row0 + l31;
    if (lh == 0 && grow < N_NODES) {
      unsigned* o = cand + ((size_t)grow * NCH + chunk) * 16;
#pragma unroll
      for (int i = 0; i < 16; i += 4)
        *(uint4*)(o + i) = make_uint4(run[i], run[i + 1], run[i + 2], run[i + 3]);
    }
  } else {
    // ---------------- vertex conv (knn-independent branches) ----------------
    int vid = q3 * 2 + (r3 - 1);
    if (vid >= 2500) return;
    int zz = vid / 625, bi = vid - zz * 625;
    int n0 = bi * 16;
    int* idxLm = (int*)smem;
    float* coefPm = (float*)(smem + 2112);
    float* coefSm = (float*)(smem + 10560);
    if (zz < 3) {
      vc16_body(tid, n0, zz, idxLm, coefPm, coefSm, fH16, wH16,
                cluster_idx, NCB * 16, zz * 16, 0, bKK_c, wK1_c, bK1_c, hx);
    } else {
      vc32_body(tid, n0, idxLm, coefPm, coefSm, fH16, wH16,
                struct_idx, bKK_s, wK1_s, bK1_s, hx);
    }
  }
}

// ---------------- knn vertex conv (after krerank) ----------------
__global__ __launch_bounds__(256, 4) void kvc3(
    const _Float16* __restrict__ fH16, const _Float16* __restrict__ wH16,
    const int* __restrict__ knn,
    const float* __restrict__ bKK_n, const float* __restrict__ wK1_n,
    const float* __restrict__ bK1_n, float* __restrict__ hx) {
  __shared__ __align__(16) unsigned char smem[12672];
  int* idxLm = (int*)smem;
  float* coefPm = (float*)(smem + 2112);
  float* coefSm = (float*)(smem + 10560);
  vc16_body(threadIdx.x, blockIdx.x * 16, 3, idxLm, coefPm, coefSm, fH16, wH16,
            knn, 16, 0, 32768, bKK_n, wK1_n, bK1_n, hx);
}

// ---------------- merge chunk keys -> top-32 candidate cols ----------------
__global__ __launch_bounds__(64) void kmerge(const unsigned* __restrict__ cand,
                                             int* __restrict__ candIdx) {
  int row = blockIdx.x * 64 + threadIdx.x;
  if (row >= N_NODES) return;
  unsigned long long run[TOPM];
#pragma unroll
  for (int s = 0; s < TOPM; s++) run[s] = 0ull;
  const uint4* c4 = (const uint4*)(cand + (size_t)row * (NCH * 16));
  for (int ch = 0; ch < NCH; ch++) {
    unsigned b[16];
#pragma unroll
    for (int q = 0; q < 4; q++) {
      uint4 t = c4[ch * 4 + q];
      b[q * 4 + 0] = t.x; b[q * 4 + 1] = t.y;
      b[q * 4 + 2] = t.z; b[q * 4 + 3] = t.w;
    }
    unsigned base = (unsigned)(ch * CHUNK);
    unsigned long long b64[16];
#pragma unroll
    for (int s = 0; s < 16; s++) {
      unsigned k = b[s];
      unsigned gcol = base + (1023u - (k & 1023u));
      b64[s] = ((unsigned long long)(k >> 10) << 32) | (unsigned long long)(~gcol);
    }
#pragma unroll
    for (int i = 0; i < 16; i++) run[i] = max(run[i], b64[15 - i]);
#pragma unroll
    for (int j = 16; j > 0; j >>= 1)
#pragma unroll
      for (int i = 0; i < TOPM; i++)
        if ((i & j) == 0) ceu64(run[i], run[i + j]);
  }
  int4* o4 = (int4*)(candIdx + (size_t)row * TOPM);
#pragma unroll
  for (int s = 0; s < TOPM; s += 4) {
    int4 o;
    o.x = (int)(~(unsigned)(run[s + 0] & 0xFFFFFFFFull));
    o.y = (int)(~(unsigned)(run[s + 1] & 0xFFFFFFFFull));
    o.z = (int)(~(unsigned)(run[s + 2] & 0xFFFFFFFFull));
    o.w = (int)(~(unsigned)(run[s + 3] & 0xFFFFFFFFull));
    o4[s >> 2] = o;
  }
}

// ---------------- f64 exact re-rank of 32 candidates -> knn top-16 ----------------
__global__ __launch_bounds__(256) void krerank(const float* __restrict__ feats,
                                               const double* __restrict__ normD,
                                               const int* __restrict__ candIdx,
                                               int* __restrict__ knn) {
  __shared__ float rowF[D];
  __shared__ double simL[TOPM];
  __shared__ int idxL[TOPM];
  int row = blockIdx.x;
  int tid = threadIdx.x;
  if (tid < DQ)
    ((float4*)rowF)[tid] = ((const float4*)(feats + (size_t)row * D))[tid];
  int c = tid >> 3, part = tid & 7;
  int cnd = candIdx[(size_t)row * TOPM + c];
  __syncthreads();
  const float4* f4 = (const float4*)(feats + (size_t)cnd * D);
  double acc = 0.0;
#pragma unroll
  for (int g = 0; g < 4; g++) {
    float4 v = f4[part * 4 + g];
    const float* rf = &rowF[(part * 4 + g) * 4];
    acc = fma((double)v.x, (double)rf[0], acc);
    acc = fma((double)v.y, (double)rf[1], acc);
    acc = fma((double)v.z, (double)rf[2], acc);
    acc = fma((double)v.w, (double)rf[3], acc);
  }
  acc += __shfl_down(acc, 4);
  acc += __shfl_down(acc, 2);
  acc += __shfl_down(acc, 1);
  if (part == 0) {
    simL[c] = acc / (normD[row] * normD[cnd]);
    idxL[c] = cnd;
  }
  __syncthreads();
  if (tid < TOPM) {
    double s = simL[tid];
    int idx = idxL[tid];
    int rank = 0;
#pragma unroll
    for (int o = 0; o < TOPM; o++) {
      double so = simL[o];
      int io = idxL[o];
      rank += (so > s || (so == s && io < idx)) ? 1 : 0;
    }
    if (rank < TOPK) knn[(size_t)row * TOPK + rank] = idx;
  }
}

// ---------------- edge attention + fc (float4 LDS) ----------------
__global__ __launch_bounds__(256) void kfinal(const float* __restrict__ hx,
    const float* __restrict__ w1, const float* __restrict__ b1,
    const float* __restrict__ w2, const float* __restrict__ b2p,
    const float* __restrict__ fcw, const float* __restrict__ fcb,
    float* __restrict__ out) {
  __shared__ float xL[8][T_HE][D];
  __shared__ float hL[8][T_HE][HID_SZ];
  __shared__ float scL[8][T_HE];
  __shared__ float aggL[8][D];
  int tid = threadIdx.x;
  int n0 = blockIdx.x * 8;
  const float4* hx4 = (const float4*)hx;
  for (int q = tid; q < 8 * T_HE * DQ; q += 256) {
    int nn = q / (T_HE * DQ);
    int rem = q - nn * (T_HE * DQ);
    int t = rem / DQ;
    int dq = rem & 31;
    int node = n0 + nn;
    float4 val = make_float4(0.f, 0.f, 0.f, 0.f);
    if (node < N_NODES) val = hx4[((size_t)node * T_HE + t) * DQ + dq];
    *(float4*)&xL[nn][t][dq << 2] = val;
  }
  __syncthreads();
  for (int q = tid; q < 8 * T_HE * HID_SZ; q += 256) {
    int nn = q / (T_HE * HID_SZ);
    int rem = q - nn * (T_HE * HID_SZ);
    int t = rem / HID_SZ;
    int hh = rem & (HID_SZ - 1);
    float acc = b1[hh];
    const float4* xv4 = (const float4*)xL[nn][t];
    for (int dq = 0; dq < 32; dq++) {
      float4 xv = xv4[dq];
      int db = dq * 4;
      acc = fmaf(xv.x, w1[(db + 0) * HID_SZ + hh], acc);
      acc = fmaf(xv.y, w1[(db + 1) * HID_SZ + hh], acc);
      acc = fmaf(xv.z, w1[(db + 2) * HID_SZ + hh], acc);
      acc = fmaf(xv.w, w1[(db + 3) * HID_SZ + hh], acc);
    }
    hL[nn][t][hh] = fmaxf(acc, 0.f);
  }
  __syncthreads();
  if (tid < 8 * T_HE) {
    int nn = tid / T_HE, t = tid % T_HE;
    float acc = b2p[0];
    for (int hh = 0; hh < HID_SZ; hh++) acc = fmaf(hL[nn][t][hh], w2[hh], acc);
    scL[nn][t] = acc;
  }
  __syncthreads();
  if (tid < 8) {
    float mx = -1e30f;
#pragma unroll
    for (int t = 0; t < T_HE; t++) mx = fmaxf(mx, scL[tid][t]);
    float e[T_HE];
    float s = 0.f;
#pragma unroll
    for (int t = 0; t < T_HE; t++) { e[t] = expf(scL[tid][t] - mx); s += e[t]; }
    float inv = 1.f / s;
#pragma unroll
    for (int t = 0; t < T_HE; t++) scL[tid][t] = e[t] * inv;
  }
  __syncthreads();
  {
    int nn = tid >> 5, dq = tid & 31;
    float4 acc = make_float4(0.f, 0.f, 0.f, 0.f);
#pragma unroll
    for (int t = 0; t < T_HE; t++) {
      float sw = scL[nn][t];
      float4 xv = *(const float4*)&xL[nn][t][dq << 2];
      acc.x = fmaf(sw, xv.x, acc.x);
      acc.y = fmaf(sw, xv.y, acc.y);
      acc.z = fmaf(sw, xv.z, acc.z);
      acc.w = fmaf(sw, xv.w, acc.w);
    }
    *(float4*)&aggL[nn][dq << 2] = acc;
  }
  __syncthreads();
  {
    int dout = tid & 127, g = tid >> 7;
    float a0 = fcb[dout], a1 = a0, a2 = a0, a3 = a0;
    for (int dq = 0; dq < 32; dq++) {
      int db = dq * 4;
      float wv0 = fcw[(db + 0) * 128 + dout];
      float wv1 = fcw[(db + 1) * 128 + dout];
      float wv2 = fcw[(db + 2) * 128 + dout];
      float wv3 = fcw[(db + 3) * 128 + dout];
      float4 v0 = *(const float4*)&aggL[g * 4 + 0][db];
      float4 v1 = *(const float4*)&aggL[g * 4 + 1][db];
      float4 v2 = *(const float4*)&aggL[g * 4 + 2][db];
      float4 v3 = *(const float4*)&aggL[g * 4 + 3][db];
      a0 = fmaf(v0.x, wv0, fmaf(v0.y, wv1, fmaf(v0.z, wv2, fmaf(v0.w, wv3, a0))));
      a1 = fmaf(v1.x, wv0, fmaf(v1.y, wv1, fmaf(v1.z, wv2, fmaf(v1.w, wv3, a1))));
      a2 = fmaf(v2.x, wv0, fmaf(v2.y, wv1, fmaf(v2.z, wv2, fmaf(v2.w, wv3, a2))));
      a3 = fmaf(v3.x, wv0, fmaf(v3.y, wv1, fmaf(v3.z, wv2, fmaf(v3.w, wv3, a3))));
    }
    int nb = n0 + g * 4;
    if (nb + 0 < N_NODES) out[(size_t)(nb + 0) * 128 + dout] = fmaxf(a0, 0.f);
    if (nb + 1 < N_NODES) out[(size_t)(nb + 1) * 128 + dout] = fmaxf(a1, 0.f);
    if (nb + 2 < N_NODES) out[(size_t)(nb + 2) * 128 + dout] = fmaxf(a2, 0.f);
    if (nb + 3 < N_NODES) out[(size_t)(nb + 3) * 128 + dout] = fmaxf(a3, 0.f);
  }
}

extern "C" void kernel_launch(void* const* d_in, const int* in_sizes, int n_in,
                              void* d_out, int out_size, void* d_ws, size_t ws_size,
                              hipStream_t stream) {
  (void)in_sizes; (void)n_in; (void)out_size; (void)ws_size;
  const float* feats       = (const float*)d_in[1];
  const int*   cluster_idx = (const int*)d_in[2];
  const int*   struct_idx  = (const int*)d_in[3];
  const float* wKK_c = (const float*)d_in[5];
  const float* bKK_c = (const float*)d_in[6];
  const float* wK1_c = (const float*)d_in[7];
  const float* bK1_c = (const float*)d_in[8];
  const float* wKK_n = (const float*)d_in[9];
  const float* bKK_n = (const float*)d_in[10];
  const float* wK1_n = (const float*)d_in[11];
  const float* bK1_n = (const float*)d_in[12];
  const float* wKK_s = (const float*)d_in[13];
  const float* bKK_s = (const float*)d_in[14];
  const float* wK1_s = (const float*)d_in[15];
  const float* bK1_s = (const float*)d_in[16];
  const float* ec_w1 = (const float*)d_in[17];
  const float* ec_b1 = (const float*)d_in[18];
  const float* ec_w2 = (const float*)d_in[19];
  const float* ec_b2 = (const float*)d_in[20];
  const float* fc_w  = (const float*)d_in[21];
  const float* fc_b  = (const float*)d_in[22];
  float* out = (float*)d_out;

  // ws layout (lifetime-overlapped, <= 72.32 MB):
  //  [0, 2.56M)         xnh (bf16)
  //  [2.56M, 12.8M)     cand (u32)
  //  [12.8M, 14.08M)    candIdx (int)
  //  [14.08M, 14.16M)   normD (f64)
  //  [14.16M, 16.72M)   fH16 (fp16 feats, 2.56 MB)
  //  [16.72M, 17.12M)   wH16 (fp16 W: c|n|s = 32768|32768|131072 halves)
  //  [46.08M, 46.72M)   knn (int)
  //  [46.72M, 72.32M)   hx (f32)
  char* wsb = (char*)d_ws;
  unsigned short* xnh = (unsigned short*)(wsb);
  unsigned* cand = (unsigned*)(wsb + 2560000);
  int* candIdx = (int*)(wsb + 12800000);
  double* normD = (double*)(wsb + 14080000);
  _Float16* fH16 = (_Float16*)(wsb + 14160000);
  _Float16* wH16 = (_Float16*)(wsb + 16720000);
  int* knnIdx = (int*)(wsb + 46080000);
  float* hx = (float*)(wsb + 46720000);

  kpre<<<2884, 256, 0, stream>>>(feats, wKK_c, wKK_n, wKK_s,
                                 xnh, fH16, normD, wH16);
  ksimvc<<<3792, 256, 0, stream>>>(xnh, cand, fH16, wH16, cluster_idx, struct_idx,
                                   bKK_c, bKK_s, wK1_c, bK1_c, wK1_s, bK1_s, hx);
  kmerge<<<(N_NODES + 63) / 64, 64, 0, stream>>>(cand, candIdx);
  krerank<<<N_NODES, 256, 0, stream>>>(feats, normD, candIdx, knnIdx);
  kvc3<<<625, 256, 0, stream>>>(fH16, wH16, knnIdx, bKK_n, wK1_n, bK1_n, hx);
  kfinal<<<1250, 256, 0, stream>>>(hx, ec_w1, ec_b1, ec_w2, ec_b2, fc_w, fc_b, out);
}